// Round 1
// baseline (1164.281 us; speedup 1.0000x reference)
//
#include <hip/hip_runtime.h>
#include <cstddef>
#include <cstdint>

#define NB 8
#define CIN 256
#define HH 32
#define WW 32
#define LL 1024
#define DKC 512
#define DVC 256
#define NHD 8
#define DKH 64
#define DVH 32
#define QKVC 1280

// ---------------- QKV projection GEMM ----------------
// qkv[b,o,s] = sum_k W[o,k] * X[b,k,s];  q part (o<512) scaled by 1/8
__global__ __launch_bounds__(256) void qkv_kernel(
    const float* __restrict__ X, const float* __restrict__ W,
    float* __restrict__ qkv) {
  __shared__ float sW[16][68];
  __shared__ float sX[16][64];
  const int b = blockIdx.z;
  const int o0 = blockIdx.x * 64;
  const int s0 = blockIdx.y * 64;
  const int tid = threadIdx.x;
  const int ty = tid >> 4, tx = tid & 15;
  float acc[4][4] = {};
  const float* Xb = X + (size_t)b * CIN * LL;
  for (int k0 = 0; k0 < CIN; k0 += 16) {
    {
      const int m = tid >> 2;
      const int kq = (tid & 3) * 4;
      const float4 w4 = *(const float4*)(W + (size_t)(o0 + m) * CIN + k0 + kq);
      sW[kq + 0][m] = w4.x; sW[kq + 1][m] = w4.y;
      sW[kq + 2][m] = w4.z; sW[kq + 3][m] = w4.w;
    }
    {
      const int kk = tid >> 4;
      const int j = (tid & 15) * 4;
      *(float4*)&sX[kk][j] = *(const float4*)(Xb + (size_t)(k0 + kk) * LL + s0 + j);
    }
    __syncthreads();
#pragma unroll
    for (int kk = 0; kk < 16; ++kk) {
      const float4 a4 = *(const float4*)&sW[kk][ty * 4];
      const float4 b4 = *(const float4*)&sX[kk][tx * 4];
      const float av[4] = {a4.x, a4.y, a4.z, a4.w};
      const float bv[4] = {b4.x, b4.y, b4.z, b4.w};
#pragma unroll
      for (int i = 0; i < 4; ++i)
#pragma unroll
        for (int j = 0; j < 4; ++j) acc[i][j] += av[i] * bv[j];
    }
    __syncthreads();
  }
#pragma unroll
  for (int i = 0; i < 4; ++i) {
    const int o = o0 + ty * 4 + i;
    const float sc = (o < DKC) ? 0.125f : 1.0f;
    float4 r;
    r.x = acc[i][0] * sc; r.y = acc[i][1] * sc;
    r.z = acc[i][2] * sc; r.w = acc[i][3] * sc;
    *(float4*)(qkv + ((size_t)b * QKVC + o) * LL + s0 + tx * 4) = r;
  }
}

// ---------------- Flash attention with relative logits ----------------
// grid = B*NH*(L/32) blocks, 256 threads. TQ=32 query rows, TK=64 key cols.
// logits[s,t] = q[:,s].k[:,t] + qT.rel_w[:, (t>>5)-(s>>5)+31] + qT.rel_h[:, (t&31)-(s&31)+31]
// where qT = q[:, sT], sT = (s&31)*32 + (s>>5).
__global__ __launch_bounds__(256) void attn_kernel(
    const float* __restrict__ qkv, const float* __restrict__ krh,
    const float* __restrict__ krw, float* __restrict__ attnbuf) {
  __shared__ float qs[DKH][36];      // q[c][row]
  __shared__ float ks[DKH][68];      // k tile [c][tt]; pre-loop overlaid as qT staging
  __shared__ float vs[64][36];       // v tile [tt][cv]
  __shared__ float ss[32][68];       // P tile [row][tt]
  __shared__ float rws[32][64];      // per-row rel_w table
  __shared__ float rhs[32][64];      // per-row rel_h table
  __shared__ float rm[32], rl[32], alphas[32];

  const int blk = blockIdx.x;
  const int qt = blk & 31;
  const int bn = blk >> 5;
  const int n = bn & 7, b = bn >> 3;
  const int s0 = qt * 32;
  const int a = qt;                  // s0 >> 5
  const int tid = threadIdx.x;

  const float* qb = qkv + ((size_t)b * QKVC + n * DKH) * LL;
  const float* kb = qkv + ((size_t)b * QKVC + DKC + n * DKH) * LL;
  const float* vb = qkv + ((size_t)b * QKVC + 2 * DKC + n * DVH) * LL;

  // overlay: qT staging reuses the ks buffer before the K-loop
  float (*qTs)[33] = reinterpret_cast<float(*)[33]>(&ks[0][0]);

  {
    const int i = tid & 31;
    const int c0 = tid >> 5;  // 0..7
#pragma unroll
    for (int r = 0; r < 8; ++r) {
      const int c = c0 + r * 8;
      qs[c][i] = qb[(size_t)c * LL + s0 + i];
      // sT for row i (s0 % 32 == 0): sT = i*32 + a
      qTs[c][i] = qb[(size_t)c * LL + i * 32 + a];
    }
  }
  if (tid < 32) { rm[tid] = -1e30f; rl[tid] = 0.f; }
  __syncthreads();

  // per-row rel tables: 32 rows x (63 rw + 63 rh) dot-64s
  for (int idx = tid; idx < 4032; idx += 256) {
    const int row = idx / 126;
    const int r = idx - row * 126;
    const float* tab = (r < 63) ? krw : krh;
    const int m = (r < 63) ? r : (r - 63);
    float acc = 0.f;
#pragma unroll
    for (int c = 0; c < DKH; ++c) acc += qTs[c][row] * tab[c * 63 + m];
    if (r < 63) rws[row][m] = acc; else rhs[row][m] = acc;
  }
  __syncthreads();   // also fences qTs before ks overwrite

  const int rg = tid >> 5;        // row group: rows rg*4 .. rg*4+3
  const int cg = tid & 31;        // col group: cols cg*2, cg*2+1
  const int i0 = rg * 4;
  const int tt0 = cg * 2;
  const int io = tid >> 3;        // PV row
  const int cv0 = (tid & 7) * 4;  // PV v-channel base

  float oacc[4] = {0.f, 0.f, 0.f, 0.f};

  for (int kt = 0; kt < 16; ++kt) {
    const int t0 = kt * 64;
    {
      const int tt = tid & 63;
      const int c0 = tid >> 6;
#pragma unroll
      for (int r = 0; r < 16; ++r) {
        const int c = c0 + r * 4;
        ks[c][tt] = kb[(size_t)c * LL + t0 + tt];
      }
#pragma unroll
      for (int r = 0; r < 8; ++r) {
        const int cv = c0 + r * 4;
        vs[tt][cv] = vb[(size_t)cv * LL + t0 + tt];
      }
    }
    __syncthreads();

    // S tile: each thread 4 rows x 2 cols
    float sv[4][2] = {};
#pragma unroll 8
    for (int c = 0; c < DKH; ++c) {
      const float4 q4 = *(const float4*)&qs[c][i0];
      const float2 k2 = *(const float2*)&ks[c][tt0];
      sv[0][0] += q4.x * k2.x; sv[0][1] += q4.x * k2.y;
      sv[1][0] += q4.y * k2.x; sv[1][1] += q4.y * k2.y;
      sv[2][0] += q4.z * k2.x; sv[2][1] += q4.z * k2.y;
      sv[3][0] += q4.w * k2.x; sv[3][1] += q4.w * k2.y;
    }
    const int mw = ((t0 + tt0) >> 5) - a + 31;   // same for tt0 and tt0+1 (tt0 even)
    const int mh0 = (tt0 & 31) + 31;
#pragma unroll
    for (int ii = 0; ii < 4; ++ii) {
      const int i = i0 + ii;
      const float rwv = rws[i][mw];
      sv[ii][0] += rwv + rhs[i][mh0 - i];
      sv[ii][1] += rwv + rhs[i][mh0 + 1 - i];
    }
    // online softmax per row (32 lanes own one row-group's columns)
#pragma unroll
    for (int ii = 0; ii < 4; ++ii) {
      const int i = i0 + ii;
      float tmax = fmaxf(sv[ii][0], sv[ii][1]);
#pragma unroll
      for (int off = 16; off; off >>= 1)
        tmax = fmaxf(tmax, __shfl_down(tmax, off, 32));
      tmax = __shfl(tmax, 0, 32);
      const float rmold = rm[i];
      const float newm = fmaxf(rmold, tmax);
      const float alpha = __expf(rmold - newm);
      const float e0 = __expf(sv[ii][0] - newm);
      const float e1 = __expf(sv[ii][1] - newm);
      ss[i][tt0] = e0; ss[i][tt0 + 1] = e1;
      float psum = e0 + e1;
#pragma unroll
      for (int off = 16; off; off >>= 1)
        psum += __shfl_down(psum, off, 32);
      if (cg == 0) {
        rl[i] = rl[i] * alpha + psum;
        rm[i] = newm;
        alphas[i] = alpha;
      }
    }
    __syncthreads();

    // PV: thread owns (io, cv0..cv0+3)
    const float al = alphas[io];
#pragma unroll
    for (int j = 0; j < 4; ++j) oacc[j] *= al;
    for (int tt = 0; tt < 64; ++tt) {
      const float pv = ss[io][tt];
      const float4 v4 = *(const float4*)&vs[tt][cv0];
      oacc[0] += pv * v4.x; oacc[1] += pv * v4.y;
      oacc[2] += pv * v4.z; oacc[3] += pv * v4.w;
    }
    __syncthreads();
  }

  const float inv = 1.0f / rl[io];
#pragma unroll
  for (int j = 0; j < 4; ++j)
    attnbuf[((size_t)b * DVC + n * DVH + cv0 + j) * LL + s0 + io] = oacc[j] * inv;
}

// ---------------- output projection GEMM ----------------
// out[b, 256+o, s] = sum_c Wout[o,c] * A[b,c,s]
__global__ __launch_bounds__(256) void proj_kernel(
    const float* __restrict__ A, const float* __restrict__ W,
    float* __restrict__ out) {
  __shared__ float sW[16][68];
  __shared__ float sX[16][64];
  const int b = blockIdx.z;
  const int o0 = blockIdx.x * 64;
  const int s0 = blockIdx.y * 64;
  const int tid = threadIdx.x;
  const int ty = tid >> 4, tx = tid & 15;
  float acc[4][4] = {};
  const float* Ab = A + (size_t)b * DVC * LL;
  for (int k0 = 0; k0 < DVC; k0 += 16) {
    {
      const int m = tid >> 2;
      const int kq = (tid & 3) * 4;
      const float4 w4 = *(const float4*)(W + (size_t)(o0 + m) * DVC + k0 + kq);
      sW[kq + 0][m] = w4.x; sW[kq + 1][m] = w4.y;
      sW[kq + 2][m] = w4.z; sW[kq + 3][m] = w4.w;
    }
    {
      const int kk = tid >> 4;
      const int j = (tid & 15) * 4;
      *(float4*)&sX[kk][j] = *(const float4*)(Ab + (size_t)(k0 + kk) * LL + s0 + j);
    }
    __syncthreads();
#pragma unroll
    for (int kk = 0; kk < 16; ++kk) {
      const float4 a4 = *(const float4*)&sW[kk][ty * 4];
      const float4 b4 = *(const float4*)&sX[kk][tx * 4];
      const float av[4] = {a4.x, a4.y, a4.z, a4.w};
      const float bv[4] = {b4.x, b4.y, b4.z, b4.w};
#pragma unroll
      for (int i = 0; i < 4; ++i)
#pragma unroll
        for (int j = 0; j < 4; ++j) acc[i][j] += av[i] * bv[j];
    }
    __syncthreads();
  }
#pragma unroll
  for (int i = 0; i < 4; ++i) {
    const int o = o0 + ty * 4 + i;
    float4 r;
    r.x = acc[i][0]; r.y = acc[i][1]; r.z = acc[i][2]; r.w = acc[i][3];
    *(float4*)(out + ((size_t)b * 512 + 256 + o) * LL + s0 + tx * 4) = r;
  }
}

// ---------------- 3x3 conv, pad 1 ----------------
// block: 16 output channels x (8h x 32w) spatial tile
__global__ __launch_bounds__(256) void conv_kernel(
    const float* __restrict__ x, const float* __restrict__ wconv,
    float* __restrict__ out) {
  __shared__ float xs[10][34];
  __shared__ float wblk[16][12];
  const int og = blockIdx.x;  // 0..15
  const int ht = blockIdx.y;  // 0..3
  const int b = blockIdx.z;
  const int tx = threadIdx.x & 31;
  const int ty = threadIdx.x >> 5;
  const int h0 = ht * 8;
  const int o0 = og * 16;
  float acc[16] = {};
  const float* xb = x + (size_t)b * CIN * LL;
  for (int ci = 0; ci < CIN; ++ci) {
    for (int li = threadIdx.x; li < 340; li += 256) {
      const int rr = li / 34;
      const int ccol = li - rr * 34;
      const int gh = h0 - 1 + rr;
      const int gw = ccol - 1;
      float v = 0.f;
      if (gh >= 0 && gh < 32 && gw >= 0 && gw < 32)
        v = xb[(size_t)ci * LL + gh * 32 + gw];
      xs[rr][ccol] = v;
    }
    if (threadIdx.x < 144) {
      const int oo = threadIdx.x / 9;
      const int j = threadIdx.x - oo * 9;
      wblk[oo][j] = wconv[(size_t)(o0 + oo) * 2304 + ci * 9 + j];
    }
    __syncthreads();
    float r00 = xs[ty + 0][tx + 0], r01 = xs[ty + 0][tx + 1], r02 = xs[ty + 0][tx + 2];
    float r10 = xs[ty + 1][tx + 0], r11 = xs[ty + 1][tx + 1], r12 = xs[ty + 1][tx + 2];
    float r20 = xs[ty + 2][tx + 0], r21 = xs[ty + 2][tx + 1], r22 = xs[ty + 2][tx + 2];
#pragma unroll
    for (int oo = 0; oo < 16; ++oo) {
      const float4 w0 = *(const float4*)&wblk[oo][0];
      const float4 w1 = *(const float4*)&wblk[oo][4];
      const float w8 = wblk[oo][8];
      acc[oo] += r00 * w0.x + r01 * w0.y + r02 * w0.z
               + r10 * w0.w + r11 * w1.x + r12 * w1.y
               + r20 * w1.z + r21 * w1.w + r22 * w8;
    }
    __syncthreads();
  }
#pragma unroll
  for (int oo = 0; oo < 16; ++oo)
    out[((size_t)b * 512 + o0 + oo) * LL + (h0 + ty) * 32 + tx] = acc[oo];
}

extern "C" void kernel_launch(void* const* d_in, const int* in_sizes, int n_in,
                              void* d_out, int out_size, void* d_ws, size_t ws_size,
                              hipStream_t stream) {
  const float* x     = (const float*)d_in[0];
  const float* wqkv  = (const float*)d_in[1];
  const float* wconv = (const float*)d_in[2];
  const float* wout  = (const float*)d_in[3];
  const float* krh   = (const float*)d_in[4];
  const float* krw   = (const float*)d_in[5];
  float* out = (float*)d_out;
  float* qkv = (float*)d_ws;                       // 8*1280*1024 floats = 40 MB
  float* attnbuf = qkv + (size_t)NB * QKVC * LL;   // 8*256*1024 floats  =  8 MB

  qkv_kernel<<<dim3(20, 16, NB), 256, 0, stream>>>(x, wqkv, qkv);
  conv_kernel<<<dim3(16, 4, NB), 256, 0, stream>>>(x, wconv, out);
  attn_kernel<<<dim3(2048), 256, 0, stream>>>(qkv, krh, krw, attnbuf);
  proj_kernel<<<dim3(4, 16, NB), 256, 0, stream>>>(attnbuf, wout, out);
}

// Round 2
// 671.502 us; speedup vs baseline: 1.7338x; 1.7338x over previous
//
#include <hip/hip_runtime.h>
#include <cstddef>
#include <cstdint>

#define NB 8
#define CIN 256
#define LL 1024
#define DKC 512
#define DVC 256
#define QKVC 1280

typedef short short8 __attribute__((ext_vector_type(8)));
typedef float f32x4 __attribute__((ext_vector_type(4)));

__device__ __forceinline__ unsigned short f2bf(float f) {
  unsigned int u = __float_as_uint(f);
  u += 0x7fffu + ((u >> 16) & 1u);
  return (unsigned short)(u >> 16);
}

// ---------------- QKV projection GEMM (fp32 in, bf16 out, layout-split) ----
// q -> qbf [b][h][s][c] (scaled 1/8), k -> kbf [b][h][t][c], v -> vbf [b][c][t]
__global__ __launch_bounds__(256) void qkv_kernel(
    const float* __restrict__ X, const float* __restrict__ W,
    unsigned short* __restrict__ qbf, unsigned short* __restrict__ kbf,
    unsigned short* __restrict__ vbf) {
  __shared__ float sW[16][68];
  __shared__ float sX[16][64];
  __shared__ float trans[64][65];
  const int b = blockIdx.z;
  const int o0 = blockIdx.x * 64;
  const int s0 = blockIdx.y * 64;
  const int tid = threadIdx.x;
  const int ty = tid >> 4, tx = tid & 15;
  float acc[4][4] = {};
  const float* Xb = X + (size_t)b * CIN * LL;
  for (int k0 = 0; k0 < CIN; k0 += 16) {
    {
      const int m = tid >> 2;
      const int kq = (tid & 3) * 4;
      const float4 w4 = *(const float4*)(W + (size_t)(o0 + m) * CIN + k0 + kq);
      sW[kq + 0][m] = w4.x; sW[kq + 1][m] = w4.y;
      sW[kq + 2][m] = w4.z; sW[kq + 3][m] = w4.w;
    }
    {
      const int kk = tid >> 4;
      const int j = (tid & 15) * 4;
      *(float4*)&sX[kk][j] = *(const float4*)(Xb + (size_t)(k0 + kk) * LL + s0 + j);
    }
    __syncthreads();
#pragma unroll
    for (int kk = 0; kk < 16; ++kk) {
      const float4 a4 = *(const float4*)&sW[kk][ty * 4];
      const float4 b4 = *(const float4*)&sX[kk][tx * 4];
      const float av[4] = {a4.x, a4.y, a4.z, a4.w};
      const float bv[4] = {b4.x, b4.y, b4.z, b4.w};
#pragma unroll
      for (int i = 0; i < 4; ++i)
#pragma unroll
        for (int j = 0; j < 4; ++j) acc[i][j] += av[i] * bv[j];
    }
    __syncthreads();
  }
  if (o0 < 2 * DKC) {
    // q or k tile: transpose via LDS, write bf16 [s][c] rows
    const float sc = (o0 < DKC) ? 0.125f : 1.0f;
#pragma unroll
    for (int i = 0; i < 4; ++i)
#pragma unroll
      for (int j = 0; j < 4; ++j)
        trans[ty * 4 + i][tx * 4 + j] = acc[i][j] * sc;
    __syncthreads();
    const int sl = tid >> 2;
    const int c0 = (tid & 3) * 16;
    unsigned short buf[16];
#pragma unroll
    for (int m = 0; m < 16; ++m) buf[m] = f2bf(trans[c0 + m][sl]);
    unsigned short* dst;
    int head;
    if (o0 < DKC) { dst = qbf; head = o0 >> 6; }
    else { dst = kbf; head = (o0 - DKC) >> 6; }
    const size_t base = (((size_t)(b * 8 + head)) * LL + s0 + sl) * 64 + c0;
    *(uint4*)(dst + base) = *(uint4*)&buf[0];
    *(uint4*)(dst + base + 8) = *(uint4*)&buf[8];
  } else {
    // v tile: keep c-major, bf16
    const int c0v = o0 - 2 * DKC;
#pragma unroll
    for (int i = 0; i < 4; ++i) {
      const int c = c0v + ty * 4 + i;
      unsigned short pk[4];
#pragma unroll
      for (int j = 0; j < 4; ++j) pk[j] = f2bf(acc[i][j]);
      *(ushort4*)(vbf + ((size_t)b * DVC + c) * LL + s0 + tx * 4) = *(ushort4*)&pk[0];
    }
  }
}

// ---------------- rel-table prep: (64,63) fp32 -> transposed padded (64,64) bf16
__global__ __launch_bounds__(256) void prep_rel(
    const float* __restrict__ krh, const float* __restrict__ krw,
    unsigned short* __restrict__ relTh, unsigned short* __restrict__ relTw) {
  const int idx = blockIdx.x * 256 + threadIdx.x;  // 0..8191
  const int tbl = idx >> 12;
  const int rest = idx & 4095;
  const int m = rest >> 6, c = rest & 63;
  const float* src = tbl ? krw : krh;
  unsigned short* dst = tbl ? relTw : relTh;
  const float v = (m < 63) ? src[c * 63 + m] : 0.f;
  dst[m * 64 + c] = f2bf(v);
}

// ---------------- MFMA flash attention with relative logits ----------------
// block: 64 q-rows (16/wave), K-loop 64 keys/iter.
// logits[s,t] = q.k + RW[s][(t>>5)-a+31] + RH[s][(t&31)-p+31], table rows from
// qT(s)=q[:,sT], sT=(s&31)*32+(s>>5); tables computed by MFMA GEMM in prologue.
__global__ __launch_bounds__(256, 3) void attn_kernel(
    const unsigned short* __restrict__ qbf, const unsigned short* __restrict__ kbf,
    const unsigned short* __restrict__ vbf, const unsigned short* __restrict__ relTh,
    const unsigned short* __restrict__ relTw, float* __restrict__ attnbuf) {
  __shared__ __align__(16) char smem[53248];
  unsigned short* ks = (unsigned short*)smem;            // [64][64] swizzled bf16
  unsigned short* vs = (unsigned short*)(smem + 8192);   // [32][64] swizzled bf16
  unsigned short* ps = (unsigned short*)(smem + 12288);  // 4 x [16][64] swizzled
  float* rwt = (float*)(smem + 20480);                   // [64][64]
  float* rht = (float*)(smem + 36864);                   // [64][64]
  float* obuf = (float*)smem;                            // [32][68] overlay

  const int tid = threadIdx.x;
  const int lane = tid & 63, w = tid >> 6;
  const int n16 = lane & 15, quad = lane >> 4;
  const int blk = blockIdx.x;
  const int qb = blk & 15, n = (blk >> 4) & 7, b = blk >> 7;
  const int s0 = qb * 64;
  const int aa = 2 * qb + (w >> 1);   // s>>5, uniform per wave
  const int pb = (w & 1) * 16;        // p = pb + quad*4 + reg

  const unsigned short* qbase = qbf + ((size_t)(b * 8 + n)) * LL * 64;
  const unsigned short* kbase = kbf + ((size_t)(b * 8 + n)) * LL * 64;
  const unsigned short* vbase = vbf + ((size_t)(b * 8 + n)) * 32 * LL;

  // ---- prologue: rel tables via MFMA (rows are wave-private) ----
  {
    const int sT = (pb + n16) * 32 + aa;
    short8 ra0 = *(const short8*)(qbase + (size_t)sT * 64 + quad * 8);
    short8 ra1 = *(const short8*)(qbase + (size_t)sT * 64 + 32 + quad * 8);
#pragma unroll
    for (int tbl = 0; tbl < 2; ++tbl) {
      const unsigned short* rel = tbl ? relTh : relTw;
      f32x4 acc[4];
#pragma unroll
      for (int mt = 0; mt < 4; ++mt) acc[mt] = (f32x4){0.f, 0.f, 0.f, 0.f};
#pragma unroll
      for (int mt = 0; mt < 4; ++mt) {
        short8 b0 = *(const short8*)(rel + (mt * 16 + n16) * 64 + quad * 8);
        short8 b1 = *(const short8*)(rel + (mt * 16 + n16) * 64 + 32 + quad * 8);
        acc[mt] = __builtin_amdgcn_mfma_f32_16x16x32_bf16(ra0, b0, acc[mt], 0, 0, 0);
        acc[mt] = __builtin_amdgcn_mfma_f32_16x16x32_bf16(ra1, b1, acc[mt], 0, 0, 0);
      }
      float* dst = tbl ? rht : rwt;
#pragma unroll
      for (int mt = 0; mt < 4; ++mt)
#pragma unroll
        for (int reg = 0; reg < 4; ++reg)
          dst[(w * 16 + quad * 4 + reg) * 64 + mt * 16 + n16] = acc[mt][reg];
    }
  }
  // Q fragments (rows s0 + w*16 + n16)
  short8 qf0 = *(const short8*)(qbase + (size_t)(s0 + w * 16 + n16) * 64 + quad * 8);
  short8 qf1 = *(const short8*)(qbase + (size_t)(s0 + w * 16 + n16) * 64 + 32 + quad * 8);

  float m_st[4], l_st[4];
#pragma unroll
  for (int r = 0; r < 4; ++r) { m_st[r] = -1e30f; l_st[r] = 0.f; }
  f32x4 oacc[2];
  oacc[0] = (f32x4){0.f, 0.f, 0.f, 0.f};
  oacc[1] = (f32x4){0.f, 0.f, 0.f, 0.f};

  unsigned short* psw = ps + w * 1024;
  const int ck = tid & 7;
  const int trow = tid >> 3;  // 0..31

  for (int kt64 = 0; kt64 < 16; ++kt64) {
    const int t0 = kt64 * 64;
    __syncthreads();
    {
      const unsigned short* kg = kbase + (size_t)t0 * 64;
      uint4 d0 = *(const uint4*)(kg + trow * 64 + ck * 8);
      uint4 d1 = *(const uint4*)(kg + (trow + 32) * 64 + ck * 8);
      uint4 d2 = *(const uint4*)(vbase + (size_t)trow * LL + t0 + ck * 8);
      *(uint4*)&ks[trow * 64 + ((ck ^ (trow & 7)) * 8)] = d0;
      *(uint4*)&ks[(trow + 32) * 64 + ((ck ^ (trow & 7)) * 8)] = d1;
      *(uint4*)&vs[trow * 64 + ((ck ^ (trow & 7)) * 8)] = d2;
    }
    __syncthreads();

    // QK^T: S tile 16x64 per wave
    f32x4 sacc[4];
#pragma unroll
    for (int tt = 0; tt < 4; ++tt) sacc[tt] = (f32x4){0.f, 0.f, 0.f, 0.f};
#pragma unroll
    for (int tt = 0; tt < 4; ++tt) {
      short8 kb0 = *(const short8*)&ks[(tt * 16 + n16) * 64 + ((quad ^ (n16 & 7)) * 8)];
      short8 kb1 = *(const short8*)&ks[(tt * 16 + n16) * 64 + (((quad + 4) ^ (n16 & 7)) * 8)];
      sacc[tt] = __builtin_amdgcn_mfma_f32_16x16x32_bf16(qf0, kb0, sacc[tt], 0, 0, 0);
      sacc[tt] = __builtin_amdgcn_mfma_f32_16x16x32_bf16(qf1, kb1, sacc[tt], 0, 0, 0);
    }
    // rel bias (C layout: col = n16 within tile, row = quad*4+reg)
#pragma unroll
    for (int tt = 0; tt < 4; ++tt) {
      const int mw = (t0 >> 5) + (tt >> 1) - aa + 31;
      const int mhb = (tt & 1) * 16 + n16 + 31 - pb;
#pragma unroll
      for (int reg = 0; reg < 4; ++reg) {
        const int iL = quad * 4 + reg;
        sacc[tt][reg] += rwt[(w * 16 + iL) * 64 + mw] + rht[(w * 16 + iL) * 64 + mhb - iL];
      }
    }
    // online softmax per row
    float ee[4][4];
    float alpha[4];
#pragma unroll
    for (int reg = 0; reg < 4; ++reg) {
      float mx = fmaxf(fmaxf(sacc[0][reg], sacc[1][reg]), fmaxf(sacc[2][reg], sacc[3][reg]));
#pragma unroll
      for (int m = 1; m < 16; m <<= 1) mx = fmaxf(mx, __shfl_xor(mx, m, 16));
      const float nm = fmaxf(m_st[reg], mx);
      alpha[reg] = __expf(m_st[reg] - nm);
      float rs = 0.f;
#pragma unroll
      for (int tt = 0; tt < 4; ++tt) {
        const float e = __expf(sacc[tt][reg] - nm);
        ee[tt][reg] = e;
        rs += e;
      }
#pragma unroll
      for (int m = 1; m < 16; m <<= 1) rs += __shfl_xor(rs, m, 16);
      l_st[reg] = l_st[reg] * alpha[reg] + rs;
      m_st[reg] = nm;
    }
    // write P (bf16) into wave-private LDS, A-frag-ready swizzled layout
#pragma unroll
    for (int tt = 0; tt < 4; ++tt)
#pragma unroll
      for (int reg = 0; reg < 4; ++reg) {
        const int r = quad * 4 + reg;
        psw[r * 64 + (((tt * 2 + (n16 >> 3)) ^ (r & 7)) * 8) + (n16 & 7)] = f2bf(ee[tt][reg]);
      }
    // rescale O accumulator
#pragma unroll
    for (int ct = 0; ct < 2; ++ct)
#pragma unroll
      for (int reg = 0; reg < 4; ++reg) oacc[ct][reg] *= alpha[reg];
    __asm__ volatile("s_waitcnt lgkmcnt(0)" ::: "memory");
    // P @ V
#pragma unroll
    for (int kt = 0; kt < 2; ++kt) {
      short8 pa = *(const short8*)&psw[n16 * 64 + (((quad + 4 * kt) ^ (n16 & 7)) * 8)];
#pragma unroll
      for (int ct = 0; ct < 2; ++ct) {
        short8 vb = *(const short8*)&vs[(ct * 16 + n16) * 64 + (((quad + 4 * kt) ^ (n16 & 7)) * 8)];
        oacc[ct] = __builtin_amdgcn_mfma_f32_16x16x32_bf16(pa, vb, oacc[ct], 0, 0, 0);
      }
    }
  }
  __syncthreads();
#pragma unroll
  for (int ct = 0; ct < 2; ++ct)
#pragma unroll
    for (int reg = 0; reg < 4; ++reg)
      obuf[(ct * 16 + n16) * 68 + (w * 16 + quad * 4 + reg)] = oacc[ct][reg] / l_st[reg];
  __syncthreads();
  {
    const int cvr = tid >> 3;
    const int sc = (tid & 7) * 8;
    float4 x0 = *(float4*)&obuf[cvr * 68 + sc];
    float4 x1 = *(float4*)&obuf[cvr * 68 + sc + 4];
    float* dst = attnbuf + ((size_t)b * DVC + n * 32 + cvr) * LL + s0 + sc;
    *(float4*)dst = x0;
    *(float4*)(dst + 4) = x1;
  }
}

// ---------------- output projection GEMM ----------------
__global__ __launch_bounds__(256) void proj_kernel(
    const float* __restrict__ A, const float* __restrict__ W,
    float* __restrict__ out) {
  __shared__ float sW[16][68];
  __shared__ float sX[16][64];
  const int b = blockIdx.z;
  const int o0 = blockIdx.x * 64;
  const int s0 = blockIdx.y * 64;
  const int tid = threadIdx.x;
  const int ty = tid >> 4, tx = tid & 15;
  float acc[4][4] = {};
  const float* Ab = A + (size_t)b * DVC * LL;
  for (int k0 = 0; k0 < DVC; k0 += 16) {
    {
      const int m = tid >> 2;
      const int kq = (tid & 3) * 4;
      const float4 w4 = *(const float4*)(W + (size_t)(o0 + m) * DVC + k0 + kq);
      sW[kq + 0][m] = w4.x; sW[kq + 1][m] = w4.y;
      sW[kq + 2][m] = w4.z; sW[kq + 3][m] = w4.w;
    }
    {
      const int kk = tid >> 4;
      const int j = (tid & 15) * 4;
      *(float4*)&sX[kk][j] = *(const float4*)(Ab + (size_t)(k0 + kk) * LL + s0 + j);
    }
    __syncthreads();
#pragma unroll
    for (int kk = 0; kk < 16; ++kk) {
      const float4 a4 = *(const float4*)&sW[kk][ty * 4];
      const float4 b4 = *(const float4*)&sX[kk][tx * 4];
      const float av[4] = {a4.x, a4.y, a4.z, a4.w};
      const float bv[4] = {b4.x, b4.y, b4.z, b4.w};
#pragma unroll
      for (int i = 0; i < 4; ++i)
#pragma unroll
        for (int j = 0; j < 4; ++j) acc[i][j] += av[i] * bv[j];
    }
    __syncthreads();
  }
#pragma unroll
  for (int i = 0; i < 4; ++i) {
    const int o = o0 + ty * 4 + i;
    float4 r;
    r.x = acc[i][0]; r.y = acc[i][1]; r.z = acc[i][2]; r.w = acc[i][3];
    *(float4*)(out + ((size_t)b * 512 + 256 + o) * LL + s0 + tx * 4) = r;
  }
}

// ---------------- 3x3 conv, pad 1 ----------------
__global__ __launch_bounds__(256) void conv_kernel(
    const float* __restrict__ x, const float* __restrict__ wconv,
    float* __restrict__ out) {
  __shared__ float xs[10][34];
  __shared__ float wblk[16][12];
  const int og = blockIdx.x;
  const int ht = blockIdx.y;
  const int b = blockIdx.z;
  const int tx = threadIdx.x & 31;
  const int ty = threadIdx.x >> 5;
  const int h0 = ht * 8;
  const int o0 = og * 16;
  float acc[16] = {};
  const float* xb = x + (size_t)b * CIN * LL;
  for (int ci = 0; ci < CIN; ++ci) {
    for (int li = threadIdx.x; li < 340; li += 256) {
      const int rr = li / 34;
      const int ccol = li - rr * 34;
      const int gh = h0 - 1 + rr;
      const int gw = ccol - 1;
      float v = 0.f;
      if (gh >= 0 && gh < 32 && gw >= 0 && gw < 32)
        v = xb[(size_t)ci * LL + gh * 32 + gw];
      xs[rr][ccol] = v;
    }
    if (threadIdx.x < 144) {
      const int oo = threadIdx.x / 9;
      const int j = threadIdx.x - oo * 9;
      wblk[oo][j] = wconv[(size_t)(o0 + oo) * 2304 + ci * 9 + j];
    }
    __syncthreads();
    float r00 = xs[ty + 0][tx + 0], r01 = xs[ty + 0][tx + 1], r02 = xs[ty + 0][tx + 2];
    float r10 = xs[ty + 1][tx + 0], r11 = xs[ty + 1][tx + 1], r12 = xs[ty + 1][tx + 2];
    float r20 = xs[ty + 2][tx + 0], r21 = xs[ty + 2][tx + 1], r22 = xs[ty + 2][tx + 2];
#pragma unroll
    for (int oo = 0; oo < 16; ++oo) {
      const float4 w0 = *(const float4*)&wblk[oo][0];
      const float4 w1 = *(const float4*)&wblk[oo][4];
      const float w8 = wblk[oo][8];
      acc[oo] += r00 * w0.x + r01 * w0.y + r02 * w0.z
               + r10 * w0.w + r11 * w1.x + r12 * w1.y
               + r20 * w1.z + r21 * w1.w + r22 * w8;
    }
    __syncthreads();
  }
#pragma unroll
  for (int oo = 0; oo < 16; ++oo)
    out[((size_t)b * 512 + o0 + oo) * LL + (h0 + ty) * 32 + tx] = acc[oo];
}

extern "C" void kernel_launch(void* const* d_in, const int* in_sizes, int n_in,
                              void* d_out, int out_size, void* d_ws, size_t ws_size,
                              hipStream_t stream) {
  const float* x     = (const float*)d_in[0];
  const float* wqkv  = (const float*)d_in[1];
  const float* wconv = (const float*)d_in[2];
  const float* wout  = (const float*)d_in[3];
  const float* krh   = (const float*)d_in[4];
  const float* krw   = (const float*)d_in[5];
  float* out = (float*)d_out;

  unsigned short* qbf = (unsigned short*)d_ws;                 // 8*8*1024*64
  unsigned short* kbf = qbf + (size_t)NB * 8 * LL * 64;        // 4,194,304 elems each
  unsigned short* vbf = kbf + (size_t)NB * 8 * LL * 64;        // 8*256*1024
  float* attnbuf = (float*)(vbf + (size_t)NB * DVC * LL);      // 8*256*1024 fp32
  unsigned short* relTh = (unsigned short*)(attnbuf + (size_t)NB * DVC * LL);
  unsigned short* relTw = relTh + 4096;

  prep_rel<<<dim3(32), 256, 0, stream>>>(krh, krw, relTh, relTw);
  qkv_kernel<<<dim3(20, 16, NB), 256, 0, stream>>>(x, wqkv, qbf, kbf, vbf);
  conv_kernel<<<dim3(16, 4, NB), 256, 0, stream>>>(x, wconv, out);
  attn_kernel<<<dim3(1024), 256, 0, stream>>>(qbf, kbf, vbf, relTh, relTw, attnbuf);
  proj_kernel<<<dim3(4, 16, NB), 256, 0, stream>>>(attnbuf, wout, out);
}

// Round 3
// 272.080 us; speedup vs baseline: 4.2792x; 2.4680x over previous
//
#include <hip/hip_runtime.h>
#include <cstddef>
#include <cstdint>

#define NB 8
#define CIN 256
#define LL 1024
#define DKC 512
#define DVC 256
#define QKVC 1280
#define XPSTRIDE 295936  // 34*34*256

typedef short short8 __attribute__((ext_vector_type(8)));
typedef float f32x4 __attribute__((ext_vector_type(4)));

__device__ __forceinline__ unsigned short f2bf(float f) {
  unsigned int u = __float_as_uint(f);
  u += 0x7fffu + ((u >> 16) & 1u);
  return (unsigned short)(u >> 16);
}

// ---------------- QKV projection GEMM (fp32 in, bf16 out, layout-split) ----
__global__ __launch_bounds__(256) void qkv_kernel(
    const float* __restrict__ X, const float* __restrict__ W,
    unsigned short* __restrict__ qbf, unsigned short* __restrict__ kbf,
    unsigned short* __restrict__ vbf) {
  __shared__ float sW[16][68];
  __shared__ float sX[16][64];
  __shared__ float trans[64][65];
  const int b = blockIdx.z;
  const int o0 = blockIdx.x * 64;
  const int s0 = blockIdx.y * 64;
  const int tid = threadIdx.x;
  const int ty = tid >> 4, tx = tid & 15;
  float acc[4][4] = {};
  const float* Xb = X + (size_t)b * CIN * LL;
  for (int k0 = 0; k0 < CIN; k0 += 16) {
    {
      const int m = tid >> 2;
      const int kq = (tid & 3) * 4;
      const float4 w4 = *(const float4*)(W + (size_t)(o0 + m) * CIN + k0 + kq);
      sW[kq + 0][m] = w4.x; sW[kq + 1][m] = w4.y;
      sW[kq + 2][m] = w4.z; sW[kq + 3][m] = w4.w;
    }
    {
      const int kk = tid >> 4;
      const int j = (tid & 15) * 4;
      *(float4*)&sX[kk][j] = *(const float4*)(Xb + (size_t)(k0 + kk) * LL + s0 + j);
    }
    __syncthreads();
#pragma unroll
    for (int kk = 0; kk < 16; ++kk) {
      const float4 a4 = *(const float4*)&sW[kk][ty * 4];
      const float4 b4 = *(const float4*)&sX[kk][tx * 4];
      const float av[4] = {a4.x, a4.y, a4.z, a4.w};
      const float bv[4] = {b4.x, b4.y, b4.z, b4.w};
#pragma unroll
      for (int i = 0; i < 4; ++i)
#pragma unroll
        for (int j = 0; j < 4; ++j) acc[i][j] += av[i] * bv[j];
    }
    __syncthreads();
  }
  if (o0 < 2 * DKC) {
    const float sc = (o0 < DKC) ? 0.125f : 1.0f;
#pragma unroll
    for (int i = 0; i < 4; ++i)
#pragma unroll
      for (int j = 0; j < 4; ++j)
        trans[ty * 4 + i][tx * 4 + j] = acc[i][j] * sc;
    __syncthreads();
    const int sl = tid >> 2;
    const int c0 = (tid & 3) * 16;
    unsigned short buf[16];
#pragma unroll
    for (int m = 0; m < 16; ++m) buf[m] = f2bf(trans[c0 + m][sl]);
    unsigned short* dst;
    int head;
    if (o0 < DKC) { dst = qbf; head = o0 >> 6; }
    else { dst = kbf; head = (o0 - DKC) >> 6; }
    const size_t base = (((size_t)(b * 8 + head)) * LL + s0 + sl) * 64 + c0;
    *(uint4*)(dst + base) = *(uint4*)&buf[0];
    *(uint4*)(dst + base + 8) = *(uint4*)&buf[8];
  } else {
    const int c0v = o0 - 2 * DKC;
#pragma unroll
    for (int i = 0; i < 4; ++i) {
      const int c = c0v + ty * 4 + i;
      unsigned short pk[4];
#pragma unroll
      for (int j = 0; j < 4; ++j) pk[j] = f2bf(acc[i][j]);
      *(ushort4*)(vbf + ((size_t)b * DVC + c) * LL + s0 + tx * 4) = *(ushort4*)&pk[0];
    }
  }
}

// ---------------- rel-table prep ----------------
__global__ __launch_bounds__(256) void prep_rel(
    const float* __restrict__ krh, const float* __restrict__ krw,
    unsigned short* __restrict__ relTh, unsigned short* __restrict__ relTw) {
  const int idx = blockIdx.x * 256 + threadIdx.x;
  const int tbl = idx >> 12;
  const int rest = idx & 4095;
  const int m = rest >> 6, c = rest & 63;
  const float* src = tbl ? krw : krh;
  unsigned short* dst = tbl ? relTw : relTh;
  const float v = (m < 63) ? src[c * 63 + m] : 0.f;
  dst[m * 64 + c] = f2bf(v);
}

// ---------------- conv prep: x -> padded transposed bf16 [b][34][34][c] ----
__global__ __launch_bounds__(256) void xpad_border(unsigned short* __restrict__ xTp) {
  const int idx = blockIdx.x * 256 + threadIdx.x;  // 0 .. 8*132*256
  const int b = idx / 33792;
  const int rem = idx - b * 33792;
  const int pos = rem >> 8, c = rem & 255;
  int hp, wp;
  if (pos < 34) { hp = 0; wp = pos; }
  else if (pos < 68) { hp = 33; wp = pos - 34; }
  else if (pos < 100) { hp = pos - 68 + 1; wp = 0; }
  else { hp = pos - 100 + 1; wp = 33; }
  xTp[(size_t)b * XPSTRIDE + (hp * 34 + wp) * 256 + c] = 0;
}

__global__ __launch_bounds__(256) void xpad_interior(
    const float* __restrict__ x, unsigned short* __restrict__ xTp) {
  __shared__ float tile[64][65];
  const int st = blockIdx.x;  // 0..15 (2 image rows each)
  const int b = blockIdx.y;
  const int s0 = st * 64;
  const int h0 = st * 2;
  const int tid = threadIdx.x;
  for (int cc = 0; cc < 4; ++cc) {
    const int c0 = cc * 64;
    {
      const int row = tid >> 2;
      const int j0 = (tid & 3) * 16;
#pragma unroll
      for (int k = 0; k < 4; ++k)
        *(float4*)&tile[row][j0 + k * 4] =
            *(const float4*)(x + ((size_t)(b * CIN + c0 + row)) * LL + s0 + j0 + k * 4);
    }
    __syncthreads();
    {
      const int sl = tid >> 2;
      const int cb = (tid & 3) * 16;
      unsigned short buf[16];
#pragma unroll
      for (int m = 0; m < 16; ++m) buf[m] = f2bf(tile[cb + m][sl]);
      const int hp = h0 + (sl >> 5) + 1;
      const int wp = (sl & 31) + 1;
      unsigned short* dst = xTp + (size_t)b * XPSTRIDE + (hp * 34 + wp) * 256 + c0 + cb;
      *(uint4*)dst = *(uint4*)&buf[0];
      *(uint4*)(dst + 8) = *(uint4*)&buf[8];
    }
    __syncthreads();
  }
}

// ---------------- conv prep: weights -> bf16 [tap][o][c] ----------------
__global__ __launch_bounds__(256) void wprep(
    const float* __restrict__ wconv, unsigned short* __restrict__ wtap) {
  const int t = blockIdx.x * 256 + threadIdx.x;  // 0 .. 589824
  const int tap = t >> 16;
  const int rem = t & 65535;
  const int o = rem >> 8, c = rem & 255;
  wtap[t] = f2bf(wconv[(size_t)(o * 256 + c) * 9 + tap]);
}

// ---------------- conv as implicit GEMM (bf16 MFMA) ----------------
// out[b][o][s] = sum_tap sum_c wtap[tap][o][c] * xTp[b][h+dh+1][w+dw+1][c]
__global__ __launch_bounds__(256) void conv_mfma(
    const unsigned short* __restrict__ xTp, const unsigned short* __restrict__ wtap,
    float* __restrict__ out) {
  __shared__ __align__(16) unsigned short as[64 * 64];
  __shared__ __align__(16) unsigned short bs[64 * 64];
  const int tid = threadIdx.x;
  const int lane = tid & 63, w = tid >> 6;
  const int n16 = lane & 15, quad = lane >> 4;
  const int ot = blockIdx.x;   // oc tile
  const int st = blockIdx.y;   // spatial tile (2 image rows)
  const int b = blockIdx.z;
  const int s0 = st * 64;
  const int h0 = st * 2;
  const int trow = tid >> 3;   // 0..31
  const int ck = tid & 7;

  const unsigned short* xb = xTp + (size_t)b * XPSTRIDE;

  f32x4 acc[4];
#pragma unroll
  for (int nt = 0; nt < 4; ++nt) acc[nt] = (f32x4){0.f, 0.f, 0.f, 0.f};

  for (int tap = 0; tap < 9; ++tap) {
    const int dh = tap / 3 - 1, dw = tap % 3 - 1;
    const unsigned short* wt = wtap + tap * 65536 + (ot * 64) * 256;
#pragma unroll
    for (int kc = 0; kc < 4; ++kc) {
      const int c0 = kc * 64;
      __syncthreads();
      {
        // A: weights, rows = oc
        uint4 a0 = *(const uint4*)(wt + (size_t)trow * 256 + c0 + ck * 8);
        uint4 a1 = *(const uint4*)(wt + (size_t)(trow + 32) * 256 + c0 + ck * 8);
        *(uint4*)&as[trow * 64 + ((ck ^ (trow & 7)) * 8)] = a0;
        *(uint4*)&as[(trow + 32) * 64 + ((ck ^ (trow & 7)) * 8)] = a1;
        // B: shifted x, rows = spatial
#pragma unroll
        for (int rr = 0; rr < 2; ++rr) {
          const int r = trow + rr * 32;
          const int hp = h0 + (r >> 5) + dh + 1;
          const int wp = (r & 31) + dw + 1;
          uint4 bx = *(const uint4*)(xb + (size_t)(hp * 34 + wp) * 256 + c0 + ck * 8);
          *(uint4*)&bs[r * 64 + ((ck ^ (r & 7)) * 8)] = bx;
        }
      }
      __syncthreads();
      short8 a0 = *(const short8*)&as[(w * 16 + n16) * 64 + ((quad ^ (n16 & 7)) * 8)];
      short8 a1 = *(const short8*)&as[(w * 16 + n16) * 64 + (((quad + 4) ^ (n16 & 7)) * 8)];
#pragma unroll
      for (int nt = 0; nt < 4; ++nt) {
        short8 b0 = *(const short8*)&bs[(nt * 16 + n16) * 64 + ((quad ^ (n16 & 7)) * 8)];
        short8 b1 = *(const short8*)&bs[(nt * 16 + n16) * 64 + (((quad + 4) ^ (n16 & 7)) * 8)];
        acc[nt] = __builtin_amdgcn_mfma_f32_16x16x32_bf16(a0, b0, acc[nt], 0, 0, 0);
        acc[nt] = __builtin_amdgcn_mfma_f32_16x16x32_bf16(a1, b1, acc[nt], 0, 0, 0);
      }
    }
  }
  // epilogue: D row = oc (quad*4+reg), col = s (nt*16+n16)
#pragma unroll
  for (int nt = 0; nt < 4; ++nt)
#pragma unroll
    for (int reg = 0; reg < 4; ++reg)
      out[((size_t)b * 512 + ot * 64 + w * 16 + quad * 4 + reg) * LL + s0 + nt * 16 + n16] =
          acc[nt][reg];
}

// ---------------- MFMA flash attention with relative logits ----------------
__global__ __launch_bounds__(256, 3) void attn_kernel(
    const unsigned short* __restrict__ qbf, const unsigned short* __restrict__ kbf,
    const unsigned short* __restrict__ vbf, const unsigned short* __restrict__ relTh,
    const unsigned short* __restrict__ relTw, float* __restrict__ attnbuf) {
  __shared__ __align__(16) char smem[53248];
  unsigned short* ks = (unsigned short*)smem;
  unsigned short* vs = (unsigned short*)(smem + 8192);
  unsigned short* ps = (unsigned short*)(smem + 12288);
  float* rwt = (float*)(smem + 20480);
  float* rht = (float*)(smem + 36864);
  float* obuf = (float*)smem;

  const int tid = threadIdx.x;
  const int lane = tid & 63, w = tid >> 6;
  const int n16 = lane & 15, quad = lane >> 4;
  const int blk = blockIdx.x;
  const int qb = blk & 15, n = (blk >> 4) & 7, b = blk >> 7;
  const int s0 = qb * 64;
  const int aa = 2 * qb + (w >> 1);
  const int pb = (w & 1) * 16;

  const unsigned short* qbase = qbf + ((size_t)(b * 8 + n)) * LL * 64;
  const unsigned short* kbase = kbf + ((size_t)(b * 8 + n)) * LL * 64;
  const unsigned short* vbase = vbf + ((size_t)(b * 8 + n)) * 32 * LL;

  {
    const int sT = (pb + n16) * 32 + aa;
    short8 ra0 = *(const short8*)(qbase + (size_t)sT * 64 + quad * 8);
    short8 ra1 = *(const short8*)(qbase + (size_t)sT * 64 + 32 + quad * 8);
#pragma unroll
    for (int tbl = 0; tbl < 2; ++tbl) {
      const unsigned short* rel = tbl ? relTh : relTw;
      f32x4 acc[4];
#pragma unroll
      for (int mt = 0; mt < 4; ++mt) acc[mt] = (f32x4){0.f, 0.f, 0.f, 0.f};
#pragma unroll
      for (int mt = 0; mt < 4; ++mt) {
        short8 b0 = *(const short8*)(rel + (mt * 16 + n16) * 64 + quad * 8);
        short8 b1 = *(const short8*)(rel + (mt * 16 + n16) * 64 + 32 + quad * 8);
        acc[mt] = __builtin_amdgcn_mfma_f32_16x16x32_bf16(ra0, b0, acc[mt], 0, 0, 0);
        acc[mt] = __builtin_amdgcn_mfma_f32_16x16x32_bf16(ra1, b1, acc[mt], 0, 0, 0);
      }
      float* dst = tbl ? rht : rwt;
#pragma unroll
      for (int mt = 0; mt < 4; ++mt)
#pragma unroll
        for (int reg = 0; reg < 4; ++reg)
          dst[(w * 16 + quad * 4 + reg) * 64 + mt * 16 + n16] = acc[mt][reg];
    }
  }
  short8 qf0 = *(const short8*)(qbase + (size_t)(s0 + w * 16 + n16) * 64 + quad * 8);
  short8 qf1 = *(const short8*)(qbase + (size_t)(s0 + w * 16 + n16) * 64 + 32 + quad * 8);

  float m_st[4], l_st[4];
#pragma unroll
  for (int r = 0; r < 4; ++r) { m_st[r] = -1e30f; l_st[r] = 0.f; }
  f32x4 oacc[2];
  oacc[0] = (f32x4){0.f, 0.f, 0.f, 0.f};
  oacc[1] = (f32x4){0.f, 0.f, 0.f, 0.f};

  unsigned short* psw = ps + w * 1024;
  const int ck = tid & 7;
  const int trow = tid >> 3;

  for (int kt64 = 0; kt64 < 16; ++kt64) {
    const int t0 = kt64 * 64;
    __syncthreads();
    {
      const unsigned short* kg = kbase + (size_t)t0 * 64;
      uint4 d0 = *(const uint4*)(kg + trow * 64 + ck * 8);
      uint4 d1 = *(const uint4*)(kg + (trow + 32) * 64 + ck * 8);
      uint4 d2 = *(const uint4*)(vbase + (size_t)trow * LL + t0 + ck * 8);
      *(uint4*)&ks[trow * 64 + ((ck ^ (trow & 7)) * 8)] = d0;
      *(uint4*)&ks[(trow + 32) * 64 + ((ck ^ (trow & 7)) * 8)] = d1;
      *(uint4*)&vs[trow * 64 + ((ck ^ (trow & 7)) * 8)] = d2;
    }
    __syncthreads();

    f32x4 sacc[4];
#pragma unroll
    for (int tt = 0; tt < 4; ++tt) sacc[tt] = (f32x4){0.f, 0.f, 0.f, 0.f};
#pragma unroll
    for (int tt = 0; tt < 4; ++tt) {
      short8 kb0 = *(const short8*)&ks[(tt * 16 + n16) * 64 + ((quad ^ (n16 & 7)) * 8)];
      short8 kb1 = *(const short8*)&ks[(tt * 16 + n16) * 64 + (((quad + 4) ^ (n16 & 7)) * 8)];
      sacc[tt] = __builtin_amdgcn_mfma_f32_16x16x32_bf16(qf0, kb0, sacc[tt], 0, 0, 0);
      sacc[tt] = __builtin_amdgcn_mfma_f32_16x16x32_bf16(qf1, kb1, sacc[tt], 0, 0, 0);
    }
#pragma unroll
    for (int tt = 0; tt < 4; ++tt) {
      const int mw = (t0 >> 5) + (tt >> 1) - aa + 31;
      const int mhb = (tt & 1) * 16 + n16 + 31 - pb;
#pragma unroll
      for (int reg = 0; reg < 4; ++reg) {
        const int iL = quad * 4 + reg;
        sacc[tt][reg] += rwt[(w * 16 + iL) * 64 + mw] + rht[(w * 16 + iL) * 64 + mhb - iL];
      }
    }
    float ee[4][4];
    float alpha[4];
#pragma unroll
    for (int reg = 0; reg < 4; ++reg) {
      float mx = fmaxf(fmaxf(sacc[0][reg], sacc[1][reg]), fmaxf(sacc[2][reg], sacc[3][reg]));
#pragma unroll
      for (int m = 1; m < 16; m <<= 1) mx = fmaxf(mx, __shfl_xor(mx, m, 16));
      const float nm = fmaxf(m_st[reg], mx);
      alpha[reg] = __expf(m_st[reg] - nm);
      float rs = 0.f;
#pragma unroll
      for (int tt = 0; tt < 4; ++tt) {
        const float e = __expf(sacc[tt][reg] - nm);
        ee[tt][reg] = e;
        rs += e;
      }
#pragma unroll
      for (int m = 1; m < 16; m <<= 1) rs += __shfl_xor(rs, m, 16);
      l_st[reg] = l_st[reg] * alpha[reg] + rs;
      m_st[reg] = nm;
    }
#pragma unroll
    for (int tt = 0; tt < 4; ++tt)
#pragma unroll
      for (int reg = 0; reg < 4; ++reg) {
        const int r = quad * 4 + reg;
        psw[r * 64 + (((tt * 2 + (n16 >> 3)) ^ (r & 7)) * 8) + (n16 & 7)] = f2bf(ee[tt][reg]);
      }
#pragma unroll
    for (int ct = 0; ct < 2; ++ct)
#pragma unroll
      for (int reg = 0; reg < 4; ++reg) oacc[ct][reg] *= alpha[reg];
    __asm__ volatile("s_waitcnt lgkmcnt(0)" ::: "memory");
#pragma unroll
    for (int kt = 0; kt < 2; ++kt) {
      short8 pa = *(const short8*)&psw[n16 * 64 + (((quad + 4 * kt) ^ (n16 & 7)) * 8)];
#pragma unroll
      for (int ct = 0; ct < 2; ++ct) {
        short8 vb = *(const short8*)&vs[(ct * 16 + n16) * 64 + (((quad + 4 * kt) ^ (n16 & 7)) * 8)];
        oacc[ct] = __builtin_amdgcn_mfma_f32_16x16x32_bf16(pa, vb, oacc[ct], 0, 0, 0);
      }
    }
  }
  __syncthreads();
#pragma unroll
  for (int ct = 0; ct < 2; ++ct)
#pragma unroll
    for (int reg = 0; reg < 4; ++reg)
      obuf[(ct * 16 + n16) * 68 + (w * 16 + quad * 4 + reg)] = oacc[ct][reg] / l_st[reg];
  __syncthreads();
  {
    const int cvr = tid >> 3;
    const int sc = (tid & 7) * 8;
    float4 x0 = *(float4*)&obuf[cvr * 68 + sc];
    float4 x1 = *(float4*)&obuf[cvr * 68 + sc + 4];
    float* dst = attnbuf + ((size_t)b * DVC + n * 32 + cvr) * LL + s0 + sc;
    *(float4*)dst = x0;
    *(float4*)(dst + 4) = x1;
  }
}

// ---------------- output projection GEMM ----------------
__global__ __launch_bounds__(256) void proj_kernel(
    const float* __restrict__ A, const float* __restrict__ W,
    float* __restrict__ out) {
  __shared__ float sW[16][68];
  __shared__ float sX[16][64];
  const int b = blockIdx.z;
  const int o0 = blockIdx.x * 64;
  const int s0 = blockIdx.y * 64;
  const int tid = threadIdx.x;
  const int ty = tid >> 4, tx = tid & 15;
  float acc[4][4] = {};
  const float* Ab = A + (size_t)b * DVC * LL;
  for (int k0 = 0; k0 < DVC; k0 += 16) {
    {
      const int m = tid >> 2;
      const int kq = (tid & 3) * 4;
      const float4 w4 = *(const float4*)(W + (size_t)(o0 + m) * DVC + k0 + kq);
      sW[kq + 0][m] = w4.x; sW[kq + 1][m] = w4.y;
      sW[kq + 2][m] = w4.z; sW[kq + 3][m] = w4.w;
    }
    {
      const int kk = tid >> 4;
      const int j = (tid & 15) * 4;
      *(float4*)&sX[kk][j] = *(const float4*)(Ab + (size_t)(k0 + kk) * LL + s0 + j);
    }
    __syncthreads();
#pragma unroll
    for (int kk = 0; kk < 16; ++kk) {
      const float4 a4 = *(const float4*)&sW[kk][ty * 4];
      const float4 b4 = *(const float4*)&sX[kk][tx * 4];
      const float av[4] = {a4.x, a4.y, a4.z, a4.w};
      const float bv[4] = {b4.x, b4.y, b4.z, b4.w};
#pragma unroll
      for (int i = 0; i < 4; ++i)
#pragma unroll
        for (int j = 0; j < 4; ++j) acc[i][j] += av[i] * bv[j];
    }
    __syncthreads();
  }
#pragma unroll
  for (int i = 0; i < 4; ++i) {
    const int o = o0 + ty * 4 + i;
    float4 r;
    r.x = acc[i][0]; r.y = acc[i][1]; r.z = acc[i][2]; r.w = acc[i][3];
    *(float4*)(out + ((size_t)b * 512 + 256 + o) * LL + s0 + tx * 4) = r;
  }
}

extern "C" void kernel_launch(void* const* d_in, const int* in_sizes, int n_in,
                              void* d_out, int out_size, void* d_ws, size_t ws_size,
                              hipStream_t stream) {
  const float* x     = (const float*)d_in[0];
  const float* wqkv  = (const float*)d_in[1];
  const float* wconv = (const float*)d_in[2];
  const float* wout  = (const float*)d_in[3];
  const float* krh   = (const float*)d_in[4];
  const float* krw   = (const float*)d_in[5];
  float* out = (float*)d_out;

  unsigned short* qbf = (unsigned short*)d_ws;
  unsigned short* kbf = qbf + (size_t)NB * 8 * LL * 64;
  unsigned short* vbf = kbf + (size_t)NB * 8 * LL * 64;
  float* attnbuf = (float*)(vbf + (size_t)NB * DVC * LL);
  unsigned short* relTh = (unsigned short*)(attnbuf + (size_t)NB * DVC * LL);
  unsigned short* relTw = relTh + 4096;
  unsigned short* xTp = relTw + 4096;                      // 8*295936 bf16
  unsigned short* wtap = xTp + (size_t)NB * XPSTRIDE;      // 9*256*256 bf16

  prep_rel<<<dim3(32), 256, 0, stream>>>(krh, krw, relTh, relTw);
  xpad_border<<<dim3(1056), 256, 0, stream>>>(xTp);
  xpad_interior<<<dim3(16, 8), 256, 0, stream>>>(x, xTp);
  wprep<<<dim3(2304), 256, 0, stream>>>(wconv, wtap);
  qkv_kernel<<<dim3(20, 16, NB), 256, 0, stream>>>(x, wqkv, qbf, kbf, vbf);
  conv_mfma<<<dim3(4, 16, NB), 256, 0, stream>>>(xTp, wtap, out);
  attn_kernel<<<dim3(1024), 256, 0, stream>>>(qbf, kbf, vbf, relTh, relTw, attnbuf);
  proj_kernel<<<dim3(4, 16, NB), 256, 0, stream>>>(attnbuf, wout, out);
}

// Round 4
// 199.922 us; speedup vs baseline: 5.8237x; 1.3609x over previous
//
#include <hip/hip_runtime.h>
#include <cstddef>
#include <cstdint>

#define NB 8
#define CIN 256
#define LL 1024
#define DKC 512
#define DVC 256
#define XPSTRIDE 295936  // 34*34*256

typedef short short8 __attribute__((ext_vector_type(8)));
typedef float f32x4 __attribute__((ext_vector_type(4)));

__device__ __forceinline__ unsigned short f2bf(float f) {
  unsigned int u = __float_as_uint(f);
  u += 0x7fffu + ((u >> 16) & 1u);
  return (unsigned short)(u >> 16);
}

// ---------------- fused weight/rel prep (fp32 -> bf16, relayout) ----------
// ranges: [0,589824) wtap [tap][o][c]; [589824,917504) wqbf [o][c] (q rows
// scaled 1/8); [917504,983040) woutbf [o][c]; [983040,991232) rel tables.
__global__ __launch_bounds__(256) void prep_weights(
    const float* __restrict__ wconv, const float* __restrict__ wqkv,
    const float* __restrict__ wout, const float* __restrict__ krh,
    const float* __restrict__ krw, unsigned short* __restrict__ wtap,
    unsigned short* __restrict__ wqbf, unsigned short* __restrict__ woutbf,
    unsigned short* __restrict__ relTh, unsigned short* __restrict__ relTw) {
  const int idx = blockIdx.x * 256 + threadIdx.x;
  if (idx < 589824) {
    const int tap = idx >> 16;
    const int rem = idx & 65535;
    wtap[idx] = f2bf(wconv[(size_t)rem * 9 + tap]);
  } else if (idx < 917504) {
    const int j = idx - 589824;
    const int o = j >> 8;
    const float sc = (o < DKC) ? 0.125f : 1.0f;
    wqbf[j] = f2bf(wqkv[j] * sc);
  } else if (idx < 983040) {
    const int j = idx - 917504;
    woutbf[j] = f2bf(wout[j]);
  } else {
    const int j = idx - 983040;
    const int tbl = j >> 12;
    const int rest = j & 4095;
    const int m = rest >> 6, c = rest & 63;
    const float* src = tbl ? krw : krh;
    unsigned short* dst = tbl ? relTw : relTh;
    const float v = (m < 63) ? src[c * 63 + m] : 0.f;
    dst[m * 64 + c] = f2bf(v);
  }
}

// ---------------- x -> padded transposed bf16 [b][34][34][c] ----------
__global__ __launch_bounds__(256) void xpad_border(unsigned short* __restrict__ xTp) {
  const int idx = blockIdx.x * 256 + threadIdx.x;
  const int b = idx / 33792;
  const int rem = idx - b * 33792;
  const int pos = rem >> 8, c = rem & 255;
  int hp, wp;
  if (pos < 34) { hp = 0; wp = pos; }
  else if (pos < 68) { hp = 33; wp = pos - 34; }
  else if (pos < 100) { hp = pos - 68 + 1; wp = 0; }
  else { hp = pos - 100 + 1; wp = 33; }
  xTp[(size_t)b * XPSTRIDE + (hp * 34 + wp) * 256 + c] = 0;
}

__global__ __launch_bounds__(256) void xpad_interior(
    const float* __restrict__ x, unsigned short* __restrict__ xTp) {
  __shared__ float tile[64][65];
  const int st = blockIdx.x;
  const int b = blockIdx.y;
  const int s0 = st * 64;
  const int h0 = st * 2;
  const int tid = threadIdx.x;
  for (int cc = 0; cc < 4; ++cc) {
    const int c0 = cc * 64;
    {
      const int row = tid >> 2;
      const int j0 = (tid & 3) * 16;
#pragma unroll
      for (int k = 0; k < 4; ++k)
        *(float4*)&tile[row][j0 + k * 4] =
            *(const float4*)(x + ((size_t)(b * CIN + c0 + row)) * LL + s0 + j0 + k * 4);
    }
    __syncthreads();
    {
      const int sl = tid >> 2;
      const int cb = (tid & 3) * 16;
      unsigned short buf[16];
#pragma unroll
      for (int m = 0; m < 16; ++m) buf[m] = f2bf(tile[cb + m][sl]);
      const int hp = h0 + (sl >> 5) + 1;
      const int wp = (sl & 31) + 1;
      unsigned short* dst = xTp + (size_t)b * XPSTRIDE + (hp * 34 + wp) * 256 + c0 + cb;
      *(uint4*)dst = *(uint4*)&buf[0];
      *(uint4*)(dst + 8) = *(uint4*)&buf[8];
    }
    __syncthreads();
  }
}

// ---------------- QKV projection as bf16 MFMA GEMM ----------------
// qkv[o,s] = sum_c wqbf[o][c] * xT[s][c]; o-tile selects q/k/v epilogue.
__global__ __launch_bounds__(256) void qkv_mfma(
    const unsigned short* __restrict__ xTp, const unsigned short* __restrict__ wqbf,
    unsigned short* __restrict__ qbf, unsigned short* __restrict__ kbf,
    unsigned short* __restrict__ vbf) {
  __shared__ __align__(16) unsigned short as[64 * 64];
  __shared__ __align__(16) unsigned short bs[64 * 64];
  __shared__ float trans[64][65];
  const int tid = threadIdx.x;
  const int lane = tid & 63, w = tid >> 6;
  const int n16 = lane & 15, quad = lane >> 4;
  const int ot = blockIdx.x;   // 0..19
  const int st = blockIdx.y;   // 0..15
  const int b = blockIdx.z;
  const int o0 = ot * 64;
  const int s0 = st * 64;
  const int h0 = st * 2;
  const int trow = tid >> 3, ck = tid & 7;

  const unsigned short* xb = xTp + (size_t)b * XPSTRIDE;
  const unsigned short* wt = wqbf + (size_t)o0 * 256;

  f32x4 acc[4];
#pragma unroll
  for (int nt = 0; nt < 4; ++nt) acc[nt] = (f32x4){0.f, 0.f, 0.f, 0.f};

#pragma unroll
  for (int kc = 0; kc < 4; ++kc) {
    const int c0 = kc * 64;
    __syncthreads();
    {
      uint4 a0 = *(const uint4*)(wt + (size_t)trow * 256 + c0 + ck * 8);
      uint4 a1 = *(const uint4*)(wt + (size_t)(trow + 32) * 256 + c0 + ck * 8);
      *(uint4*)&as[trow * 64 + ((ck ^ (trow & 7)) * 8)] = a0;
      *(uint4*)&as[(trow + 32) * 64 + ((ck ^ (trow & 7)) * 8)] = a1;
#pragma unroll
      for (int rr = 0; rr < 2; ++rr) {
        const int r = trow + rr * 32;
        const int hp = h0 + (r >> 5) + 1;
        const int wp = (r & 31) + 1;
        uint4 bx = *(const uint4*)(xb + (size_t)(hp * 34 + wp) * 256 + c0 + ck * 8);
        *(uint4*)&bs[r * 64 + ((ck ^ (r & 7)) * 8)] = bx;
      }
    }
    __syncthreads();
    short8 a0 = *(const short8*)&as[(w * 16 + n16) * 64 + ((quad ^ (n16 & 7)) * 8)];
    short8 a1 = *(const short8*)&as[(w * 16 + n16) * 64 + (((quad + 4) ^ (n16 & 7)) * 8)];
#pragma unroll
    for (int nt = 0; nt < 4; ++nt) {
      short8 b0 = *(const short8*)&bs[(nt * 16 + n16) * 64 + ((quad ^ (n16 & 7)) * 8)];
      short8 b1 = *(const short8*)&bs[(nt * 16 + n16) * 64 + (((quad + 4) ^ (n16 & 7)) * 8)];
      acc[nt] = __builtin_amdgcn_mfma_f32_16x16x32_bf16(a0, b0, acc[nt], 0, 0, 0);
      acc[nt] = __builtin_amdgcn_mfma_f32_16x16x32_bf16(a1, b1, acc[nt], 0, 0, 0);
    }
  }
  __syncthreads();
#pragma unroll
  for (int nt = 0; nt < 4; ++nt)
#pragma unroll
    for (int reg = 0; reg < 4; ++reg)
      trans[w * 16 + quad * 4 + reg][nt * 16 + n16] = acc[nt][reg];
  __syncthreads();
  const int sl = tid >> 2;
  const int cseg = (tid & 3) * 16;
  unsigned short buf[16];
  if (ot < 16) {
    // q/k: out row = s, cols = c (transpose read)
#pragma unroll
    for (int m = 0; m < 16; ++m) buf[m] = f2bf(trans[cseg + m][sl]);
    unsigned short* dst;
    int head;
    if (ot < 8) { dst = qbf; head = ot; }
    else { dst = kbf; head = ot - 8; }
    const size_t base = (((size_t)(b * 8 + head)) * LL + s0 + sl) * 64 + cseg;
    *(uint4*)(dst + base) = *(uint4*)&buf[0];
    *(uint4*)(dst + base + 8) = *(uint4*)&buf[8];
  } else {
    // v: out row = c (o-local), cols = s (direct read)
#pragma unroll
    for (int m = 0; m < 16; ++m) buf[m] = f2bf(trans[sl][cseg + m]);
    unsigned short* dst = vbf + ((size_t)b * DVC + (ot - 16) * 64 + sl) * LL + s0 + cseg;
    *(uint4*)dst = *(uint4*)&buf[0];
    *(uint4*)(dst + 8) = *(uint4*)&buf[8];
  }
}

// ---------------- conv as implicit GEMM (bf16 MFMA) ----------------
__global__ __launch_bounds__(256) void conv_mfma(
    const unsigned short* __restrict__ xTp, const unsigned short* __restrict__ wtap,
    float* __restrict__ out) {
  __shared__ __align__(16) unsigned short as[64 * 64];
  __shared__ __align__(16) unsigned short bs[64 * 64];
  const int tid = threadIdx.x;
  const int lane = tid & 63, w = tid >> 6;
  const int n16 = lane & 15, quad = lane >> 4;
  const int ot = blockIdx.x;
  const int st = blockIdx.y;
  const int b = blockIdx.z;
  const int s0 = st * 64;
  const int h0 = st * 2;
  const int trow = tid >> 3;
  const int ck = tid & 7;

  const unsigned short* xb = xTp + (size_t)b * XPSTRIDE;

  f32x4 acc[4];
#pragma unroll
  for (int nt = 0; nt < 4; ++nt) acc[nt] = (f32x4){0.f, 0.f, 0.f, 0.f};

  for (int tap = 0; tap < 9; ++tap) {
    const int dh = tap / 3 - 1, dw = tap % 3 - 1;
    const unsigned short* wt = wtap + tap * 65536 + (ot * 64) * 256;
#pragma unroll
    for (int kc = 0; kc < 4; ++kc) {
      const int c0 = kc * 64;
      __syncthreads();
      {
        uint4 a0 = *(const uint4*)(wt + (size_t)trow * 256 + c0 + ck * 8);
        uint4 a1 = *(const uint4*)(wt + (size_t)(trow + 32) * 256 + c0 + ck * 8);
        *(uint4*)&as[trow * 64 + ((ck ^ (trow & 7)) * 8)] = a0;
        *(uint4*)&as[(trow + 32) * 64 + ((ck ^ (trow & 7)) * 8)] = a1;
#pragma unroll
        for (int rr = 0; rr < 2; ++rr) {
          const int r = trow + rr * 32;
          const int hp = h0 + (r >> 5) + dh + 1;
          const int wp = (r & 31) + dw + 1;
          uint4 bx = *(const uint4*)(xb + (size_t)(hp * 34 + wp) * 256 + c0 + ck * 8);
          *(uint4*)&bs[r * 64 + ((ck ^ (r & 7)) * 8)] = bx;
        }
      }
      __syncthreads();
      short8 a0 = *(const short8*)&as[(w * 16 + n16) * 64 + ((quad ^ (n16 & 7)) * 8)];
      short8 a1 = *(const short8*)&as[(w * 16 + n16) * 64 + (((quad + 4) ^ (n16 & 7)) * 8)];
#pragma unroll
      for (int nt = 0; nt < 4; ++nt) {
        short8 b0 = *(const short8*)&bs[(nt * 16 + n16) * 64 + ((quad ^ (n16 & 7)) * 8)];
        short8 b1 = *(const short8*)&bs[(nt * 16 + n16) * 64 + (((quad + 4) ^ (n16 & 7)) * 8)];
        acc[nt] = __builtin_amdgcn_mfma_f32_16x16x32_bf16(a0, b0, acc[nt], 0, 0, 0);
        acc[nt] = __builtin_amdgcn_mfma_f32_16x16x32_bf16(a1, b1, acc[nt], 0, 0, 0);
      }
    }
  }
#pragma unroll
  for (int nt = 0; nt < 4; ++nt)
#pragma unroll
    for (int reg = 0; reg < 4; ++reg)
      out[((size_t)b * 512 + ot * 64 + w * 16 + quad * 4 + reg) * LL + s0 + nt * 16 + n16] =
          acc[nt][reg];
}

// ---------------- MFMA flash attention with relative logits ----------------
__global__ __launch_bounds__(256, 3) void attn_kernel(
    const unsigned short* __restrict__ qbf, const unsigned short* __restrict__ kbf,
    const unsigned short* __restrict__ vbf, const unsigned short* __restrict__ relTh,
    const unsigned short* __restrict__ relTw, unsigned short* __restrict__ abf) {
  __shared__ __align__(16) char smem[53248];
  unsigned short* ks = (unsigned short*)smem;
  unsigned short* vs = (unsigned short*)(smem + 8192);
  unsigned short* ps = (unsigned short*)(smem + 12288);
  float* rwt = (float*)(smem + 20480);
  float* rht = (float*)(smem + 36864);
  float* obuf = (float*)smem;  // [64][33] overlay

  const int tid = threadIdx.x;
  const int lane = tid & 63, w = tid >> 6;
  const int n16 = lane & 15, quad = lane >> 4;
  const int blk = blockIdx.x;
  const int qb = blk & 15, n = (blk >> 4) & 7, b = blk >> 7;
  const int s0 = qb * 64;
  const int aa = 2 * qb + (w >> 1);
  const int pb = (w & 1) * 16;

  const unsigned short* qbase = qbf + ((size_t)(b * 8 + n)) * LL * 64;
  const unsigned short* kbase = kbf + ((size_t)(b * 8 + n)) * LL * 64;
  const unsigned short* vbase = vbf + ((size_t)(b * 8 + n)) * 32 * LL;

  {
    const int sT = (pb + n16) * 32 + aa;
    short8 ra0 = *(const short8*)(qbase + (size_t)sT * 64 + quad * 8);
    short8 ra1 = *(const short8*)(qbase + (size_t)sT * 64 + 32 + quad * 8);
#pragma unroll
    for (int tbl = 0; tbl < 2; ++tbl) {
      const unsigned short* rel = tbl ? relTh : relTw;
      f32x4 acc[4];
#pragma unroll
      for (int mt = 0; mt < 4; ++mt) acc[mt] = (f32x4){0.f, 0.f, 0.f, 0.f};
#pragma unroll
      for (int mt = 0; mt < 4; ++mt) {
        short8 b0 = *(const short8*)(rel + (mt * 16 + n16) * 64 + quad * 8);
        short8 b1 = *(const short8*)(rel + (mt * 16 + n16) * 64 + 32 + quad * 8);
        acc[mt] = __builtin_amdgcn_mfma_f32_16x16x32_bf16(ra0, b0, acc[mt], 0, 0, 0);
        acc[mt] = __builtin_amdgcn_mfma_f32_16x16x32_bf16(ra1, b1, acc[mt], 0, 0, 0);
      }
      float* dst = tbl ? rht : rwt;
#pragma unroll
      for (int mt = 0; mt < 4; ++mt)
#pragma unroll
        for (int reg = 0; reg < 4; ++reg)
          dst[(w * 16 + quad * 4 + reg) * 64 + mt * 16 + n16] = acc[mt][reg];
    }
  }
  short8 qf0 = *(const short8*)(qbase + (size_t)(s0 + w * 16 + n16) * 64 + quad * 8);
  short8 qf1 = *(const short8*)(qbase + (size_t)(s0 + w * 16 + n16) * 64 + 32 + quad * 8);

  float m_st[4], l_st[4];
#pragma unroll
  for (int r = 0; r < 4; ++r) { m_st[r] = -1e30f; l_st[r] = 0.f; }
  f32x4 oacc[2];
  oacc[0] = (f32x4){0.f, 0.f, 0.f, 0.f};
  oacc[1] = (f32x4){0.f, 0.f, 0.f, 0.f};

  unsigned short* psw = ps + w * 1024;
  const int ck = tid & 7;
  const int trow = tid >> 3;

  for (int kt64 = 0; kt64 < 16; ++kt64) {
    const int t0 = kt64 * 64;
    __syncthreads();
    {
      const unsigned short* kg = kbase + (size_t)t0 * 64;
      uint4 d0 = *(const uint4*)(kg + trow * 64 + ck * 8);
      uint4 d1 = *(const uint4*)(kg + (trow + 32) * 64 + ck * 8);
      uint4 d2 = *(const uint4*)(vbase + (size_t)trow * LL + t0 + ck * 8);
      *(uint4*)&ks[trow * 64 + ((ck ^ (trow & 7)) * 8)] = d0;
      *(uint4*)&ks[(trow + 32) * 64 + ((ck ^ (trow & 7)) * 8)] = d1;
      *(uint4*)&vs[trow * 64 + ((ck ^ (trow & 7)) * 8)] = d2;
    }
    __syncthreads();

    f32x4 sacc[4];
#pragma unroll
    for (int tt = 0; tt < 4; ++tt) sacc[tt] = (f32x4){0.f, 0.f, 0.f, 0.f};
#pragma unroll
    for (int tt = 0; tt < 4; ++tt) {
      short8 kb0 = *(const short8*)&ks[(tt * 16 + n16) * 64 + ((quad ^ (n16 & 7)) * 8)];
      short8 kb1 = *(const short8*)&ks[(tt * 16 + n16) * 64 + (((quad + 4) ^ (n16 & 7)) * 8)];
      sacc[tt] = __builtin_amdgcn_mfma_f32_16x16x32_bf16(qf0, kb0, sacc[tt], 0, 0, 0);
      sacc[tt] = __builtin_amdgcn_mfma_f32_16x16x32_bf16(qf1, kb1, sacc[tt], 0, 0, 0);
    }
#pragma unroll
    for (int tt = 0; tt < 4; ++tt) {
      const int mw = (t0 >> 5) + (tt >> 1) - aa + 31;
      const int mhb = (tt & 1) * 16 + n16 + 31 - pb;
#pragma unroll
      for (int reg = 0; reg < 4; ++reg) {
        const int iL = quad * 4 + reg;
        sacc[tt][reg] += rwt[(w * 16 + iL) * 64 + mw] + rht[(w * 16 + iL) * 64 + mhb - iL];
      }
    }
    float ee[4][4];
    float alpha[4];
#pragma unroll
    for (int reg = 0; reg < 4; ++reg) {
      float mx = fmaxf(fmaxf(sacc[0][reg], sacc[1][reg]), fmaxf(sacc[2][reg], sacc[3][reg]));
#pragma unroll
      for (int m = 1; m < 16; m <<= 1) mx = fmaxf(mx, __shfl_xor(mx, m, 16));
      const float nm = fmaxf(m_st[reg], mx);
      alpha[reg] = __expf(m_st[reg] - nm);
      float rs = 0.f;
#pragma unroll
      for (int tt = 0; tt < 4; ++tt) {
        const float e = __expf(sacc[tt][reg] - nm);
        ee[tt][reg] = e;
        rs += e;
      }
#pragma unroll
      for (int m = 1; m < 16; m <<= 1) rs += __shfl_xor(rs, m, 16);
      l_st[reg] = l_st[reg] * alpha[reg] + rs;
      m_st[reg] = nm;
    }
#pragma unroll
    for (int tt = 0; tt < 4; ++tt)
#pragma unroll
      for (int reg = 0; reg < 4; ++reg) {
        const int r = quad * 4 + reg;
        psw[r * 64 + (((tt * 2 + (n16 >> 3)) ^ (r & 7)) * 8) + (n16 & 7)] = f2bf(ee[tt][reg]);
      }
#pragma unroll
    for (int ct = 0; ct < 2; ++ct)
#pragma unroll
      for (int reg = 0; reg < 4; ++reg) oacc[ct][reg] *= alpha[reg];
    __asm__ volatile("s_waitcnt lgkmcnt(0)" ::: "memory");
#pragma unroll
    for (int kt = 0; kt < 2; ++kt) {
      short8 pa = *(const short8*)&psw[n16 * 64 + (((quad + 4 * kt) ^ (n16 & 7)) * 8)];
#pragma unroll
      for (int ct = 0; ct < 2; ++ct) {
        short8 vb = *(const short8*)&vs[(ct * 16 + n16) * 64 + (((quad + 4 * kt) ^ (n16 & 7)) * 8)];
        oacc[ct] = __builtin_amdgcn_mfma_f32_16x16x32_bf16(pa, vb, oacc[ct], 0, 0, 0);
      }
    }
  }
  __syncthreads();
  // epilogue: write bf16 [b][s][c] (proj's B layout) via LDS transpose
#pragma unroll
  for (int ct = 0; ct < 2; ++ct)
#pragma unroll
    for (int reg = 0; reg < 4; ++reg)
      obuf[(w * 16 + quad * 4 + reg) * 33 + ct * 16 + n16] = oacc[ct][reg] / l_st[reg];
  __syncthreads();
  {
    const int row = tid >> 2;            // s within tile
    const int cseg = (tid & 3) * 8;      // cv chunk
    unsigned short buf8[8];
#pragma unroll
    for (int m = 0; m < 8; ++m) buf8[m] = f2bf(obuf[row * 33 + cseg + m]);
    *(uint4*)(abf + (((size_t)b * LL) + s0 + row) * 256 + n * 32 + cseg) = *(uint4*)&buf8[0];
  }
}

// ---------------- output projection as bf16 MFMA GEMM ----------------
// out[b,256+o,s] = sum_c woutbf[o][c] * abf[b][s][c]
__global__ __launch_bounds__(256) void proj_mfma(
    const unsigned short* __restrict__ abf, const unsigned short* __restrict__ woutbf,
    float* __restrict__ out) {
  __shared__ __align__(16) unsigned short as[64 * 64];
  __shared__ __align__(16) unsigned short bs[64 * 64];
  const int tid = threadIdx.x;
  const int lane = tid & 63, w = tid >> 6;
  const int n16 = lane & 15, quad = lane >> 4;
  const int ot = blockIdx.x;   // 0..3
  const int st = blockIdx.y;   // 0..15
  const int b = blockIdx.z;
  const int o0 = ot * 64;
  const int s0 = st * 64;
  const int trow = tid >> 3, ck = tid & 7;

  const unsigned short* ab = abf + ((size_t)b * LL + s0) * 256;
  const unsigned short* wt = woutbf + (size_t)o0 * 256;

  f32x4 acc[4];
#pragma unroll
  for (int nt = 0; nt < 4; ++nt) acc[nt] = (f32x4){0.f, 0.f, 0.f, 0.f};

#pragma unroll
  for (int kc = 0; kc < 4; ++kc) {
    const int c0 = kc * 64;
    __syncthreads();
    {
      uint4 a0 = *(const uint4*)(wt + (size_t)trow * 256 + c0 + ck * 8);
      uint4 a1 = *(const uint4*)(wt + (size_t)(trow + 32) * 256 + c0 + ck * 8);
      *(uint4*)&as[trow * 64 + ((ck ^ (trow & 7)) * 8)] = a0;
      *(uint4*)&as[(trow + 32) * 64 + ((ck ^ (trow & 7)) * 8)] = a1;
      uint4 b0 = *(const uint4*)(ab + (size_t)trow * 256 + c0 + ck * 8);
      uint4 b1 = *(const uint4*)(ab + (size_t)(trow + 32) * 256 + c0 + ck * 8);
      *(uint4*)&bs[trow * 64 + ((ck ^ (trow & 7)) * 8)] = b0;
      *(uint4*)&bs[(trow + 32) * 64 + ((ck ^ (trow & 7)) * 8)] = b1;
    }
    __syncthreads();
    short8 a0 = *(const short8*)&as[(w * 16 + n16) * 64 + ((quad ^ (n16 & 7)) * 8)];
    short8 a1 = *(const short8*)&as[(w * 16 + n16) * 64 + (((quad + 4) ^ (n16 & 7)) * 8)];
#pragma unroll
    for (int nt = 0; nt < 4; ++nt) {
      short8 b0 = *(const short8*)&bs[(nt * 16 + n16) * 64 + ((quad ^ (n16 & 7)) * 8)];
      short8 b1 = *(const short8*)&bs[(nt * 16 + n16) * 64 + (((quad + 4) ^ (n16 & 7)) * 8)];
      acc[nt] = __builtin_amdgcn_mfma_f32_16x16x32_bf16(a0, b0, acc[nt], 0, 0, 0);
      acc[nt] = __builtin_amdgcn_mfma_f32_16x16x32_bf16(a1, b1, acc[nt], 0, 0, 0);
    }
  }
#pragma unroll
  for (int nt = 0; nt < 4; ++nt)
#pragma unroll
    for (int reg = 0; reg < 4; ++reg)
      out[((size_t)b * 512 + 256 + o0 + w * 16 + quad * 4 + reg) * LL + s0 + nt * 16 + n16] =
          acc[nt][reg];
}

extern "C" void kernel_launch(void* const* d_in, const int* in_sizes, int n_in,
                              void* d_out, int out_size, void* d_ws, size_t ws_size,
                              hipStream_t stream) {
  const float* x     = (const float*)d_in[0];
  const float* wqkv  = (const float*)d_in[1];
  const float* wconv = (const float*)d_in[2];
  const float* wout  = (const float*)d_in[3];
  const float* krh   = (const float*)d_in[4];
  const float* krw   = (const float*)d_in[5];
  float* out = (float*)d_out;

  unsigned short* qbf = (unsigned short*)d_ws;              // 4,194,304
  unsigned short* kbf = qbf + (size_t)NB * 8 * LL * 64;     // 4,194,304
  unsigned short* vbf = kbf + (size_t)NB * 8 * LL * 64;     // 2,097,152
  unsigned short* abf = vbf + (size_t)NB * DVC * LL;        // 2,097,152
  unsigned short* relTh = abf + (size_t)NB * LL * DVC;      // 4096
  unsigned short* relTw = relTh + 4096;                     // 4096
  unsigned short* xTp = relTw + 4096;                       // 2,367,488
  unsigned short* wtap = xTp + (size_t)NB * XPSTRIDE;       // 589,824
  unsigned short* wqbf = wtap + 589824;                     // 327,680
  unsigned short* woutbf = wqbf + 327680;                   // 65,536

  prep_weights<<<dim3(3872), 256, 0, stream>>>(wconv, wqkv, wout, krh, krw,
                                               wtap, wqbf, woutbf, relTh, relTw);
  xpad_border<<<dim3(1056), 256, 0, stream>>>(xTp);
  xpad_interior<<<dim3(16, 8), 256, 0, stream>>>(x, xTp);
  qkv_mfma<<<dim3(20, 16, NB), 256, 0, stream>>>(xTp, wqbf, qbf, kbf, vbf);
  conv_mfma<<<dim3(4, 16, NB), 256, 0, stream>>>(xTp, wtap, out);
  attn_kernel<<<dim3(1024), 256, 0, stream>>>(qbf, kbf, vbf, relTh, relTw, abf);
  proj_mfma<<<dim3(4, 16, NB), 256, 0, stream>>>(abf, woutbf, out);
}

// Round 5
// 173.750 us; speedup vs baseline: 6.7009x; 1.1506x over previous
//
#include <hip/hip_runtime.h>
#include <cstddef>
#include <cstdint>

#define NB 8
#define CIN 256
#define LL 1024
#define DKC 512
#define DVC 256
#define XPSTRIDE 295936  // 34*34*256

typedef short short8 __attribute__((ext_vector_type(8)));
typedef float f32x4 __attribute__((ext_vector_type(4)));

__device__ __forceinline__ unsigned short f2bf(float f) {
  unsigned int u = __float_as_uint(f);
  u += 0x7fffu + ((u >> 16) & 1u);
  return (unsigned short)(u >> 16);
}
__device__ __forceinline__ float bf2f(unsigned short u) {
  return __uint_as_float(((unsigned int)u) << 16);
}

// ---------------- fused weight/rel prep (fp32 -> bf16, relayout) ----------
// q rows carry 1/8 (dkh^-0.5) AND log2(e) so attention can use exp2.
__global__ __launch_bounds__(256) void prep_weights(
    const float* __restrict__ wconv, const float* __restrict__ wqkv,
    const float* __restrict__ wout, const float* __restrict__ krh,
    const float* __restrict__ krw, unsigned short* __restrict__ wtap,
    unsigned short* __restrict__ wqbf, unsigned short* __restrict__ woutbf,
    unsigned short* __restrict__ relTh, unsigned short* __restrict__ relTw) {
  const int idx = blockIdx.x * 256 + threadIdx.x;
  if (idx < 589824) {
    const int tap = idx >> 16;
    const int rem = idx & 65535;
    wtap[idx] = f2bf(wconv[(size_t)rem * 9 + tap]);
  } else if (idx < 917504) {
    const int j = idx - 589824;
    const int o = j >> 8;
    const float sc = (o < DKC) ? 0.125f * 1.44269504088896f : 1.0f;
    wqbf[j] = f2bf(wqkv[j] * sc);
  } else if (idx < 983040) {
    const int j = idx - 917504;
    woutbf[j] = f2bf(wout[j]);
  } else {
    const int j = idx - 983040;
    const int tbl = j >> 12;
    const int rest = j & 4095;
    const int m = rest >> 6, c = rest & 63;
    const float* src = tbl ? krw : krh;
    unsigned short* dst = tbl ? relTw : relTh;
    const float v = (m < 63) ? src[c * 63 + m] : 0.f;
    dst[m * 64 + c] = f2bf(v);
  }
}

// ---------------- x -> padded transposed bf16 [b][34][34][c] ----------
__global__ __launch_bounds__(256) void xpad_border(unsigned short* __restrict__ xTp) {
  const int idx = blockIdx.x * 256 + threadIdx.x;
  const int b = idx / 33792;
  const int rem = idx - b * 33792;
  const int pos = rem >> 8, c = rem & 255;
  int hp, wp;
  if (pos < 34) { hp = 0; wp = pos; }
  else if (pos < 68) { hp = 33; wp = pos - 34; }
  else if (pos < 100) { hp = pos - 68 + 1; wp = 0; }
  else { hp = pos - 100 + 1; wp = 33; }
  xTp[(size_t)b * XPSTRIDE + (hp * 34 + wp) * 256 + c] = 0;
}

__global__ __launch_bounds__(256) void xpad_interior(
    const float* __restrict__ x, unsigned short* __restrict__ xTp) {
  __shared__ float tile[64][65];
  const int st = blockIdx.x;
  const int b = blockIdx.y;
  const int s0 = st * 64;
  const int h0 = st * 2;
  const int tid = threadIdx.x;
  for (int cc = 0; cc < 4; ++cc) {
    const int c0 = cc * 64;
    {
      const int row = tid >> 2;
      const int j0 = (tid & 3) * 16;
#pragma unroll
      for (int k = 0; k < 4; ++k)
        *(float4*)&tile[row][j0 + k * 4] =
            *(const float4*)(x + ((size_t)(b * CIN + c0 + row)) * LL + s0 + j0 + k * 4);
    }
    __syncthreads();
    {
      const int sl = tid >> 2;
      const int cb = (tid & 3) * 16;
      unsigned short buf[16];
#pragma unroll
      for (int m = 0; m < 16; ++m) buf[m] = f2bf(tile[cb + m][sl]);
      const int hp = h0 + (sl >> 5) + 1;
      const int wp = (sl & 31) + 1;
      unsigned short* dst = xTp + (size_t)b * XPSTRIDE + (hp * 34 + wp) * 256 + c0 + cb;
      *(uint4*)dst = *(uint4*)&buf[0];
      *(uint4*)(dst + 8) = *(uint4*)&buf[8];
    }
    __syncthreads();
  }
}

// ---------------- QKV projection as bf16 MFMA GEMM ----------------
__global__ __launch_bounds__(256) void qkv_mfma(
    const unsigned short* __restrict__ xTp, const unsigned short* __restrict__ wqbf,
    unsigned short* __restrict__ qbf, unsigned short* __restrict__ kbf,
    unsigned short* __restrict__ vbf) {
  __shared__ __align__(16) unsigned short as[64 * 64];
  __shared__ __align__(16) unsigned short bs[64 * 64];
  __shared__ float trans[64][65];
  const int tid = threadIdx.x;
  const int lane = tid & 63, w = tid >> 6;
  const int n16 = lane & 15, quad = lane >> 4;
  const int ot = blockIdx.x;   // 0..19
  const int st = blockIdx.y;   // 0..15
  const int b = blockIdx.z;
  const int o0 = ot * 64;
  const int s0 = st * 64;
  const int h0 = st * 2;
  const int trow = tid >> 3, ck = tid & 7;

  const unsigned short* xb = xTp + (size_t)b * XPSTRIDE;
  const unsigned short* wt = wqbf + (size_t)o0 * 256;

  f32x4 acc[4];
#pragma unroll
  for (int nt = 0; nt < 4; ++nt) acc[nt] = (f32x4){0.f, 0.f, 0.f, 0.f};

#pragma unroll
  for (int kc = 0; kc < 4; ++kc) {
    const int c0 = kc * 64;
    __syncthreads();
    {
      uint4 a0 = *(const uint4*)(wt + (size_t)trow * 256 + c0 + ck * 8);
      uint4 a1 = *(const uint4*)(wt + (size_t)(trow + 32) * 256 + c0 + ck * 8);
      *(uint4*)&as[trow * 64 + ((ck ^ (trow & 7)) * 8)] = a0;
      *(uint4*)&as[(trow + 32) * 64 + ((ck ^ (trow & 7)) * 8)] = a1;
#pragma unroll
      for (int rr = 0; rr < 2; ++rr) {
        const int r = trow + rr * 32;
        const int hp = h0 + (r >> 5) + 1;
        const int wp = (r & 31) + 1;
        uint4 bx = *(const uint4*)(xb + (size_t)(hp * 34 + wp) * 256 + c0 + ck * 8);
        *(uint4*)&bs[r * 64 + ((ck ^ (r & 7)) * 8)] = bx;
      }
    }
    __syncthreads();
    short8 a0 = *(const short8*)&as[(w * 16 + n16) * 64 + ((quad ^ (n16 & 7)) * 8)];
    short8 a1 = *(const short8*)&as[(w * 16 + n16) * 64 + (((quad + 4) ^ (n16 & 7)) * 8)];
#pragma unroll
    for (int nt = 0; nt < 4; ++nt) {
      short8 b0 = *(const short8*)&bs[(nt * 16 + n16) * 64 + ((quad ^ (n16 & 7)) * 8)];
      short8 b1 = *(const short8*)&bs[(nt * 16 + n16) * 64 + (((quad + 4) ^ (n16 & 7)) * 8)];
      acc[nt] = __builtin_amdgcn_mfma_f32_16x16x32_bf16(a0, b0, acc[nt], 0, 0, 0);
      acc[nt] = __builtin_amdgcn_mfma_f32_16x16x32_bf16(a1, b1, acc[nt], 0, 0, 0);
    }
  }
  __syncthreads();
#pragma unroll
  for (int nt = 0; nt < 4; ++nt)
#pragma unroll
    for (int reg = 0; reg < 4; ++reg)
      trans[w * 16 + quad * 4 + reg][nt * 16 + n16] = acc[nt][reg];
  __syncthreads();
  const int sl = tid >> 2;
  const int cseg = (tid & 3) * 16;
  unsigned short buf[16];
  if (ot < 16) {
#pragma unroll
    for (int m = 0; m < 16; ++m) buf[m] = f2bf(trans[cseg + m][sl]);
    unsigned short* dst;
    int head;
    if (ot < 8) { dst = qbf; head = ot; }
    else { dst = kbf; head = ot - 8; }
    const size_t base = (((size_t)(b * 8 + head)) * LL + s0 + sl) * 64 + cseg;
    *(uint4*)(dst + base) = *(uint4*)&buf[0];
    *(uint4*)(dst + base + 8) = *(uint4*)&buf[8];
  } else {
#pragma unroll
    for (int m = 0; m < 16; ++m) buf[m] = f2bf(trans[sl][cseg + m]);
    unsigned short* dst = vbf + ((size_t)b * DVC + (ot - 16) * 64 + sl) * LL + s0 + cseg;
    *(uint4*)dst = *(uint4*)&buf[0];
    *(uint4*)(dst + 8) = *(uint4*)&buf[8];
  }
}

// ---------------- conv as implicit GEMM (bf16 MFMA) ----------------
__global__ __launch_bounds__(256) void conv_mfma(
    const unsigned short* __restrict__ xTp, const unsigned short* __restrict__ wtap,
    float* __restrict__ out) {
  __shared__ __align__(16) unsigned short as[64 * 64];
  __shared__ __align__(16) unsigned short bs[64 * 64];
  const int tid = threadIdx.x;
  const int lane = tid & 63, w = tid >> 6;
  const int n16 = lane & 15, quad = lane >> 4;
  const int ot = blockIdx.x;
  const int st = blockIdx.y;
  const int b = blockIdx.z;
  const int s0 = st * 64;
  const int h0 = st * 2;
  const int trow = tid >> 3;
  const int ck = tid & 7;

  const unsigned short* xb = xTp + (size_t)b * XPSTRIDE;

  f32x4 acc[4];
#pragma unroll
  for (int nt = 0; nt < 4; ++nt) acc[nt] = (f32x4){0.f, 0.f, 0.f, 0.f};

  for (int tap = 0; tap < 9; ++tap) {
    const int dh = tap / 3 - 1, dw = tap % 3 - 1;
    const unsigned short* wt = wtap + tap * 65536 + (ot * 64) * 256;
#pragma unroll
    for (int kc = 0; kc < 4; ++kc) {
      const int c0 = kc * 64;
      __syncthreads();
      {
        uint4 a0 = *(const uint4*)(wt + (size_t)trow * 256 + c0 + ck * 8);
        uint4 a1 = *(const uint4*)(wt + (size_t)(trow + 32) * 256 + c0 + ck * 8);
        *(uint4*)&as[trow * 64 + ((ck ^ (trow & 7)) * 8)] = a0;
        *(uint4*)&as[(trow + 32) * 64 + ((ck ^ (trow & 7)) * 8)] = a1;
#pragma unroll
        for (int rr = 0; rr < 2; ++rr) {
          const int r = trow + rr * 32;
          const int hp = h0 + (r >> 5) + dh + 1;
          const int wp = (r & 31) + dw + 1;
          uint4 bx = *(const uint4*)(xb + (size_t)(hp * 34 + wp) * 256 + c0 + ck * 8);
          *(uint4*)&bs[r * 64 + ((ck ^ (r & 7)) * 8)] = bx;
        }
      }
      __syncthreads();
      short8 a0 = *(const short8*)&as[(w * 16 + n16) * 64 + ((quad ^ (n16 & 7)) * 8)];
      short8 a1 = *(const short8*)&as[(w * 16 + n16) * 64 + (((quad + 4) ^ (n16 & 7)) * 8)];
#pragma unroll
      for (int nt = 0; nt < 4; ++nt) {
        short8 b0 = *(const short8*)&bs[(nt * 16 + n16) * 64 + ((quad ^ (n16 & 7)) * 8)];
        short8 b1 = *(const short8*)&bs[(nt * 16 + n16) * 64 + (((quad + 4) ^ (n16 & 7)) * 8)];
        acc[nt] = __builtin_amdgcn_mfma_f32_16x16x32_bf16(a0, b0, acc[nt], 0, 0, 0);
        acc[nt] = __builtin_amdgcn_mfma_f32_16x16x32_bf16(a1, b1, acc[nt], 0, 0, 0);
      }
    }
  }
#pragma unroll
  for (int nt = 0; nt < 4; ++nt)
#pragma unroll
    for (int reg = 0; reg < 4; ++reg)
      out[((size_t)b * 512 + ot * 64 + w * 16 + quad * 4 + reg) * LL + s0 + nt * 16 + n16] =
          acc[nt][reg];
}

// ---------------- MFMA flash attention, fixed-max softmax ----------------
// blk remap: bn = blk&63 (head), qb = blk>>6 -> all 16 q-tiles of one head
// share blk%8 (same XCD) for K/V L2 locality.
__global__ __launch_bounds__(256, 4) void attn_kernel(
    const unsigned short* __restrict__ qbf, const unsigned short* __restrict__ kbf,
    const unsigned short* __restrict__ vbf, const unsigned short* __restrict__ relTh,
    const unsigned short* __restrict__ relTw, unsigned short* __restrict__ abf) {
  __shared__ __align__(16) char smem[28928];
  unsigned short* ks = (unsigned short*)smem;             // [64][64] swizzled
  unsigned short* vs = (unsigned short*)(smem + 8192);    // [32][64] swizzled
  unsigned short* ps = (unsigned short*)(smem + 12288);   // 4x[16][64]; rht transient
  unsigned short* rwt = (unsigned short*)(smem + 20480);  // [64][66] bf16
  float* obuf = (float*)smem;                             // [64][33] fp32 overlay

  const int tid = threadIdx.x;
  const int lane = tid & 63, w = tid >> 6;
  const int n16 = lane & 15, quad = lane >> 4;
  const int blk = blockIdx.x;
  const int bn = blk & 63, qb = blk >> 6;
  const int n = bn & 7, b = bn >> 3;
  const int s0 = qb * 64;
  const int aa = 2 * qb + (w >> 1);
  const int pb = (w & 1) * 16;

  const unsigned short* qbase = qbf + ((size_t)(b * 8 + n)) * LL * 64;
  const unsigned short* kbase = kbf + ((size_t)(b * 8 + n)) * LL * 64;
  const unsigned short* vbase = vbf + ((size_t)(b * 8 + n)) * 32 * LL;

  // ---- prologue: rel tables via MFMA; rw persistent bf16, rh transient ----
  {
    const int sT = (pb + n16) * 32 + aa;
    short8 ra0 = *(const short8*)(qbase + (size_t)sT * 64 + quad * 8);
    short8 ra1 = *(const short8*)(qbase + (size_t)sT * 64 + 32 + quad * 8);
#pragma unroll
    for (int tbl = 0; tbl < 2; ++tbl) {
      const unsigned short* rel = tbl ? relTh : relTw;
      f32x4 acc[4];
#pragma unroll
      for (int mt = 0; mt < 4; ++mt) acc[mt] = (f32x4){0.f, 0.f, 0.f, 0.f};
#pragma unroll
      for (int mt = 0; mt < 4; ++mt) {
        short8 b0 = *(const short8*)(rel + (mt * 16 + n16) * 64 + quad * 8);
        short8 b1 = *(const short8*)(rel + (mt * 16 + n16) * 64 + 32 + quad * 8);
        acc[mt] = __builtin_amdgcn_mfma_f32_16x16x32_bf16(ra0, b0, acc[mt], 0, 0, 0);
        acc[mt] = __builtin_amdgcn_mfma_f32_16x16x32_bf16(ra1, b1, acc[mt], 0, 0, 0);
      }
      if (tbl == 0) {
#pragma unroll
        for (int mt = 0; mt < 4; ++mt)
#pragma unroll
          for (int reg = 0; reg < 4; ++reg)
            rwt[(w * 16 + quad * 4 + reg) * 66 + mt * 16 + n16] = f2bf(acc[mt][reg]);
      } else {
#pragma unroll
        for (int mt = 0; mt < 4; ++mt)
#pragma unroll
          for (int reg = 0; reg < 4; ++reg)
            ps[(w * 16 + quad * 4 + reg) * 64 + mt * 16 + n16] = f2bf(acc[mt][reg]);
      }
    }
  }
  short8 qf0 = *(const short8*)(qbase + (size_t)(s0 + w * 16 + n16) * 64 + quad * 8);
  short8 qf1 = *(const short8*)(qbase + (size_t)(s0 + w * 16 + n16) * 64 + 32 + quad * 8);
  __syncthreads();
  // hoist rh bias: col index is kt-invariant -> 8 registers
  float rhreg[2][4];
#pragma unroll
  for (int tt1 = 0; tt1 < 2; ++tt1)
#pragma unroll
    for (int reg = 0; reg < 4; ++reg) {
      const int iL = quad * 4 + reg;
      rhreg[tt1][reg] = bf2f(ps[(w * 16 + iL) * 64 + tt1 * 16 + n16 + 31 - pb - iL]);
    }

  float lacc[4] = {0.f, 0.f, 0.f, 0.f};
  f32x4 oacc[2];
  oacc[0] = (f32x4){0.f, 0.f, 0.f, 0.f};
  oacc[1] = (f32x4){0.f, 0.f, 0.f, 0.f};

  unsigned short* psw = ps + w * 1024;
  const int ck = tid & 7;
  const int trow = tid >> 3;

  for (int kt64 = 0; kt64 < 16; ++kt64) {
    const int t0 = kt64 * 64;
    __syncthreads();
    {
      const unsigned short* kg = kbase + (size_t)t0 * 64;
      uint4 d0 = *(const uint4*)(kg + trow * 64 + ck * 8);
      uint4 d1 = *(const uint4*)(kg + (trow + 32) * 64 + ck * 8);
      uint4 d2 = *(const uint4*)(vbase + (size_t)trow * LL + t0 + ck * 8);
      *(uint4*)&ks[trow * 64 + ((ck ^ (trow & 7)) * 8)] = d0;
      *(uint4*)&ks[(trow + 32) * 64 + ((ck ^ (trow & 7)) * 8)] = d1;
      *(uint4*)&vs[trow * 64 + ((ck ^ (trow & 7)) * 8)] = d2;
    }
    __syncthreads();

    f32x4 sacc[4];
#pragma unroll
    for (int tt = 0; tt < 4; ++tt) sacc[tt] = (f32x4){0.f, 0.f, 0.f, 0.f};
#pragma unroll
    for (int tt = 0; tt < 4; ++tt) {
      short8 kb0 = *(const short8*)&ks[(tt * 16 + n16) * 64 + ((quad ^ (n16 & 7)) * 8)];
      short8 kb1 = *(const short8*)&ks[(tt * 16 + n16) * 64 + (((quad + 4) ^ (n16 & 7)) * 8)];
      sacc[tt] = __builtin_amdgcn_mfma_f32_16x16x32_bf16(qf0, kb0, sacc[tt], 0, 0, 0);
      sacc[tt] = __builtin_amdgcn_mfma_f32_16x16x32_bf16(qf1, kb1, sacc[tt], 0, 0, 0);
    }
    // rw bias (broadcast over n16; bank = iL at stride 66)
    float rwv[2][4];
#pragma unroll
    for (int h = 0; h < 2; ++h) {
      const int mw = (t0 >> 5) + h - aa + 31;
#pragma unroll
      for (int reg = 0; reg < 4; ++reg)
        rwv[h][reg] = bf2f(rwt[(w * 16 + quad * 4 + reg) * 66 + mw]);
    }
    // P = exp2(s + rw + rh)  (all terms carry log2e via q pre-scale)
    float ee[4][4];
#pragma unroll
    for (int tt = 0; tt < 4; ++tt)
#pragma unroll
      for (int reg = 0; reg < 4; ++reg) {
        const float e = exp2f(sacc[tt][reg] + rwv[tt >> 1][reg] + rhreg[tt & 1][reg]);
        ee[tt][reg] = e;
        lacc[reg] += e;
      }
#pragma unroll
    for (int tt = 0; tt < 4; ++tt)
#pragma unroll
      for (int reg = 0; reg < 4; ++reg) {
        const int r = quad * 4 + reg;
        psw[r * 64 + (((tt * 2 + (n16 >> 3)) ^ (r & 7)) * 8) + (n16 & 7)] = f2bf(ee[tt][reg]);
      }
    __asm__ volatile("s_waitcnt lgkmcnt(0)" ::: "memory");
#pragma unroll
    for (int kt = 0; kt < 2; ++kt) {
      short8 pa = *(const short8*)&psw[n16 * 64 + (((quad + 4 * kt) ^ (n16 & 7)) * 8)];
#pragma unroll
      for (int ct = 0; ct < 2; ++ct) {
        short8 vb = *(const short8*)&vs[(ct * 16 + n16) * 64 + (((quad + 4 * kt) ^ (n16 & 7)) * 8)];
        oacc[ct] = __builtin_amdgcn_mfma_f32_16x16x32_bf16(pa, vb, oacc[ct], 0, 0, 0);
      }
    }
  }
  // deferred row-sum reduction (cols of row r live in lanes n16 of same quad)
  float linv[4];
#pragma unroll
  for (int reg = 0; reg < 4; ++reg) {
    float l = lacc[reg];
#pragma unroll
    for (int m = 1; m < 16; m <<= 1) l += __shfl_xor(l, m, 16);
    linv[reg] = 1.0f / l;
  }
  __syncthreads();
#pragma unroll
  for (int ct = 0; ct < 2; ++ct)
#pragma unroll
    for (int reg = 0; reg < 4; ++reg)
      obuf[(w * 16 + quad * 4 + reg) * 33 + ct * 16 + n16] = oacc[ct][reg] * linv[reg];
  __syncthreads();
  {
    const int row = tid >> 2;
    const int cseg = (tid & 3) * 8;
    unsigned short buf8[8];
#pragma unroll
    for (int m = 0; m < 8; ++m) buf8[m] = f2bf(obuf[row * 33 + cseg + m]);
    *(uint4*)(abf + (((size_t)b * LL) + s0 + row) * 256 + n * 32 + cseg) = *(uint4*)&buf8[0];
  }
}

// ---------------- output projection as bf16 MFMA GEMM ----------------
__global__ __launch_bounds__(256) void proj_mfma(
    const unsigned short* __restrict__ abf, const unsigned short* __restrict__ woutbf,
    float* __restrict__ out) {
  __shared__ __align__(16) unsigned short as[64 * 64];
  __shared__ __align__(16) unsigned short bs[64 * 64];
  const int tid = threadIdx.x;
  const int lane = tid & 63, w = tid >> 6;
  const int n16 = lane & 15, quad = lane >> 4;
  const int ot = blockIdx.x;
  const int st = blockIdx.y;
  const int b = blockIdx.z;
  const int o0 = ot * 64;
  const int s0 = st * 64;
  const int trow = tid >> 3, ck = tid & 7;

  const unsigned short* ab = abf + ((size_t)b * LL + s0) * 256;
  const unsigned short* wt = woutbf + (size_t)o0 * 256;

  f32x4 acc[4];
#pragma unroll
  for (int nt = 0; nt < 4; ++nt) acc[nt] = (f32x4){0.f, 0.f, 0.f, 0.f};

#pragma unroll
  for (int kc = 0; kc < 4; ++kc) {
    const int c0 = kc * 64;
    __syncthreads();
    {
      uint4 a0 = *(const uint4*)(wt + (size_t)trow * 256 + c0 + ck * 8);
      uint4 a1 = *(const uint4*)(wt + (size_t)(trow + 32) * 256 + c0 + ck * 8);
      *(uint4*)&as[trow * 64 + ((ck ^ (trow & 7)) * 8)] = a0;
      *(uint4*)&as[(trow + 32) * 64 + ((ck ^ (trow & 7)) * 8)] = a1;
      uint4 b0 = *(const uint4*)(ab + (size_t)trow * 256 + c0 + ck * 8);
      uint4 b1 = *(const uint4*)(ab + (size_t)(trow + 32) * 256 + c0 + ck * 8);
      *(uint4*)&bs[trow * 64 + ((ck ^ (trow & 7)) * 8)] = b0;
      *(uint4*)&bs[(trow + 32) * 64 + ((ck ^ (trow & 7)) * 8)] = b1;
    }
    __syncthreads();
    short8 a0 = *(const short8*)&as[(w * 16 + n16) * 64 + ((quad ^ (n16 & 7)) * 8)];
    short8 a1 = *(const short8*)&as[(w * 16 + n16) * 64 + (((quad + 4) ^ (n16 & 7)) * 8)];
#pragma unroll
    for (int nt = 0; nt < 4; ++nt) {
      short8 b0 = *(const short8*)&bs[(nt * 16 + n16) * 64 + ((quad ^ (n16 & 7)) * 8)];
      short8 b1 = *(const short8*)&bs[(nt * 16 + n16) * 64 + (((quad + 4) ^ (n16 & 7)) * 8)];
      acc[nt] = __builtin_amdgcn_mfma_f32_16x16x32_bf16(a0, b0, acc[nt], 0, 0, 0);
      acc[nt] = __builtin_amdgcn_mfma_f32_16x16x32_bf16(a1, b1, acc[nt], 0, 0, 0);
    }
  }
#pragma unroll
  for (int nt = 0; nt < 4; ++nt)
#pragma unroll
    for (int reg = 0; reg < 4; ++reg)
      out[((size_t)b * 512 + 256 + o0 + w * 16 + quad * 4 + reg) * LL + s0 + nt * 16 + n16] =
          acc[nt][reg];
}

extern "C" void kernel_launch(void* const* d_in, const int* in_sizes, int n_in,
                              void* d_out, int out_size, void* d_ws, size_t ws_size,
                              hipStream_t stream) {
  const float* x     = (const float*)d_in[0];
  const float* wqkv  = (const float*)d_in[1];
  const float* wconv = (const float*)d_in[2];
  const float* wout  = (const float*)d_in[3];
  const float* krh   = (const float*)d_in[4];
  const float* krw   = (const float*)d_in[5];
  float* out = (float*)d_out;

  unsigned short* qbf = (unsigned short*)d_ws;
  unsigned short* kbf = qbf + (size_t)NB * 8 * LL * 64;
  unsigned short* vbf = kbf + (size_t)NB * 8 * LL * 64;
  unsigned short* abf = vbf + (size_t)NB * DVC * LL;
  unsigned short* relTh = abf + (size_t)NB * LL * DVC;
  unsigned short* relTw = relTh + 4096;
  unsigned short* xTp = relTw + 4096;
  unsigned short* wtap = xTp + (size_t)NB * XPSTRIDE;
  unsigned short* wqbf = wtap + 589824;
  unsigned short* woutbf = wqbf + 327680;

  prep_weights<<<dim3(3872), 256, 0, stream>>>(wconv, wqkv, wout, krh, krw,
                                               wtap, wqbf, woutbf, relTh, relTw);
  xpad_border<<<dim3(1056), 256, 0, stream>>>(xTp);
  xpad_interior<<<dim3(16, 8), 256, 0, stream>>>(x, xTp);
  qkv_mfma<<<dim3(20, 16, NB), 256, 0, stream>>>(xTp, wqbf, qbf, kbf, vbf);
  conv_mfma<<<dim3(4, 16, NB), 256, 0, stream>>>(xTp, wtap, out);
  attn_kernel<<<dim3(1024), 256, 0, stream>>>(qbf, kbf, vbf, relTh, relTw, abf);
  proj_mfma<<<dim3(4, 16, NB), 256, 0, stream>>>(abf, woutbf, out);
}

// Round 6
// 160.828 us; speedup vs baseline: 7.2393x; 1.0803x over previous
//
#include <hip/hip_runtime.h>
#include <cstddef>
#include <cstdint>

#define NB 8
#define CIN 256
#define LL 1024
#define DKC 512
#define DVC 256
#define XPSTRIDE 295936  // 34*34*256

typedef short short8 __attribute__((ext_vector_type(8)));
typedef float f32x4 __attribute__((ext_vector_type(4)));

__device__ __forceinline__ unsigned short f2bf(float f) {
  unsigned int u = __float_as_uint(f);
  u += 0x7fffu + ((u >> 16) & 1u);
  return (unsigned short)(u >> 16);
}
__device__ __forceinline__ float bf2f(unsigned short u) {
  return __uint_as_float(((unsigned int)u) << 16);
}

// ---------------- fused weight/rel prep (fp32 -> bf16, relayout) ----------
// q rows carry 1/8 (dkh^-0.5) AND log2(e) so attention can use exp2.
__global__ __launch_bounds__(256) void prep_weights(
    const float* __restrict__ wconv, const float* __restrict__ wqkv,
    const float* __restrict__ wout, const float* __restrict__ krh,
    const float* __restrict__ krw, unsigned short* __restrict__ wtap,
    unsigned short* __restrict__ wqbf, unsigned short* __restrict__ woutbf,
    unsigned short* __restrict__ relTh, unsigned short* __restrict__ relTw) {
  const int idx = blockIdx.x * 256 + threadIdx.x;
  if (idx < 589824) {
    const int tap = idx >> 16;
    const int rem = idx & 65535;
    wtap[idx] = f2bf(wconv[(size_t)rem * 9 + tap]);
  } else if (idx < 917504) {
    const int j = idx - 589824;
    const int o = j >> 8;
    const float sc = (o < DKC) ? 0.125f * 1.44269504088896f : 1.0f;
    wqbf[j] = f2bf(wqkv[j] * sc);
  } else if (idx < 983040) {
    const int j = idx - 917504;
    woutbf[j] = f2bf(wout[j]);
  } else {
    const int j = idx - 983040;
    const int tbl = j >> 12;
    const int rest = j & 4095;
    const int m = rest >> 6, c = rest & 63;
    const float* src = tbl ? krw : krh;
    unsigned short* dst = tbl ? relTw : relTh;
    const float v = (m < 63) ? src[c * 63 + m] : 0.f;
    dst[m * 64 + c] = f2bf(v);
  }
}

// ---------------- x -> padded transposed bf16 [b][34][34][c] ----------
__global__ __launch_bounds__(256) void xpad_border(unsigned short* __restrict__ xTp) {
  const int idx = blockIdx.x * 256 + threadIdx.x;
  const int b = idx / 33792;
  const int rem = idx - b * 33792;
  const int pos = rem >> 8, c = rem & 255;
  int hp, wp;
  if (pos < 34) { hp = 0; wp = pos; }
  else if (pos < 68) { hp = 33; wp = pos - 34; }
  else if (pos < 100) { hp = pos - 68 + 1; wp = 0; }
  else { hp = pos - 100 + 1; wp = 33; }
  xTp[(size_t)b * XPSTRIDE + (hp * 34 + wp) * 256 + c] = 0;
}

__global__ __launch_bounds__(256) void xpad_interior(
    const float* __restrict__ x, unsigned short* __restrict__ xTp) {
  __shared__ float tile[64][65];
  const int st = blockIdx.x;
  const int b = blockIdx.y;
  const int s0 = st * 64;
  const int h0 = st * 2;
  const int tid = threadIdx.x;
  for (int cc = 0; cc < 4; ++cc) {
    const int c0 = cc * 64;
    {
      const int row = tid >> 2;
      const int j0 = (tid & 3) * 16;
#pragma unroll
      for (int k = 0; k < 4; ++k)
        *(float4*)&tile[row][j0 + k * 4] =
            *(const float4*)(x + ((size_t)(b * CIN + c0 + row)) * LL + s0 + j0 + k * 4);
    }
    __syncthreads();
    {
      const int sl = tid >> 2;
      const int cb = (tid & 3) * 16;
      unsigned short buf[16];
#pragma unroll
      for (int m = 0; m < 16; ++m) buf[m] = f2bf(tile[cb + m][sl]);
      const int hp = h0 + (sl >> 5) + 1;
      const int wp = (sl & 31) + 1;
      unsigned short* dst = xTp + (size_t)b * XPSTRIDE + (hp * 34 + wp) * 256 + c0 + cb;
      *(uint4*)dst = *(uint4*)&buf[0];
      *(uint4*)(dst + 8) = *(uint4*)&buf[8];
    }
    __syncthreads();
  }
}

// ---------------- QKV projection as bf16 MFMA GEMM (reg-prefetch) --------
__global__ __launch_bounds__(256) void qkv_mfma(
    const unsigned short* __restrict__ xTp, const unsigned short* __restrict__ wqbf,
    unsigned short* __restrict__ qbf, unsigned short* __restrict__ kbf,
    unsigned short* __restrict__ vbf) {
  __shared__ __align__(16) unsigned short as[64 * 64];
  __shared__ __align__(16) unsigned short bs[64 * 64];
  __shared__ float trans[64][65];
  const int tid = threadIdx.x;
  const int lane = tid & 63, w = tid >> 6;
  const int n16 = lane & 15, quad = lane >> 4;
  const int ot = blockIdx.x;   // 0..19
  const int st = blockIdx.y;   // 0..15
  const int b = blockIdx.z;
  const int o0 = ot * 64;
  const int s0 = st * 64;
  const int h0 = st * 2;
  const int trow = tid >> 3, ck = tid & 7;

  const unsigned short* xb = xTp + (size_t)b * XPSTRIDE;
  const unsigned short* wt = wqbf + (size_t)o0 * 256;
  const int wpos = (trow & 31) + 1;

  f32x4 acc[4];
#pragma unroll
  for (int nt = 0; nt < 4; ++nt) acc[nt] = (f32x4){0.f, 0.f, 0.f, 0.f};

  uint4 ra0, ra1, rb0, rb1;
  {
    ra0 = *(const uint4*)(wt + (size_t)trow * 256 + ck * 8);
    ra1 = *(const uint4*)(wt + (size_t)(trow + 32) * 256 + ck * 8);
    rb0 = *(const uint4*)(xb + (size_t)((h0 + 1) * 34 + wpos) * 256 + ck * 8);
    rb1 = *(const uint4*)(xb + (size_t)((h0 + 2) * 34 + wpos) * 256 + ck * 8);
  }
#pragma unroll
  for (int kc = 0; kc < 4; ++kc) {
    __syncthreads();
    *(uint4*)&as[trow * 64 + ((ck ^ (trow & 7)) * 8)] = ra0;
    *(uint4*)&as[(trow + 32) * 64 + ((ck ^ (trow & 7)) * 8)] = ra1;
    *(uint4*)&bs[trow * 64 + ((ck ^ (trow & 7)) * 8)] = rb0;
    *(uint4*)&bs[(trow + 32) * 64 + ((ck ^ (trow & 7)) * 8)] = rb1;
    __syncthreads();
    if (kc < 3) {
      const int c0 = (kc + 1) * 64;
      ra0 = *(const uint4*)(wt + (size_t)trow * 256 + c0 + ck * 8);
      ra1 = *(const uint4*)(wt + (size_t)(trow + 32) * 256 + c0 + ck * 8);
      rb0 = *(const uint4*)(xb + (size_t)((h0 + 1) * 34 + wpos) * 256 + c0 + ck * 8);
      rb1 = *(const uint4*)(xb + (size_t)((h0 + 2) * 34 + wpos) * 256 + c0 + ck * 8);
    }
    short8 a0 = *(const short8*)&as[(w * 16 + n16) * 64 + ((quad ^ (n16 & 7)) * 8)];
    short8 a1 = *(const short8*)&as[(w * 16 + n16) * 64 + (((quad + 4) ^ (n16 & 7)) * 8)];
#pragma unroll
    for (int nt = 0; nt < 4; ++nt) {
      short8 b0 = *(const short8*)&bs[(nt * 16 + n16) * 64 + ((quad ^ (n16 & 7)) * 8)];
      short8 b1 = *(const short8*)&bs[(nt * 16 + n16) * 64 + (((quad + 4) ^ (n16 & 7)) * 8)];
      acc[nt] = __builtin_amdgcn_mfma_f32_16x16x32_bf16(a0, b0, acc[nt], 0, 0, 0);
      acc[nt] = __builtin_amdgcn_mfma_f32_16x16x32_bf16(a1, b1, acc[nt], 0, 0, 0);
    }
  }
  __syncthreads();
#pragma unroll
  for (int nt = 0; nt < 4; ++nt)
#pragma unroll
    for (int reg = 0; reg < 4; ++reg)
      trans[w * 16 + quad * 4 + reg][nt * 16 + n16] = acc[nt][reg];
  __syncthreads();
  const int sl = tid >> 2;
  const int cseg = (tid & 3) * 16;
  unsigned short buf[16];
  if (ot < 16) {
#pragma unroll
    for (int m = 0; m < 16; ++m) buf[m] = f2bf(trans[cseg + m][sl]);
    unsigned short* dst;
    int head;
    if (ot < 8) { dst = qbf; head = ot; }
    else { dst = kbf; head = ot - 8; }
    const size_t base = (((size_t)(b * 8 + head)) * LL + s0 + sl) * 64 + cseg;
    *(uint4*)(dst + base) = *(uint4*)&buf[0];
    *(uint4*)(dst + base + 8) = *(uint4*)&buf[8];
  } else {
#pragma unroll
    for (int m = 0; m < 16; ++m) buf[m] = f2bf(trans[sl][cseg + m]);
    unsigned short* dst = vbf + ((size_t)b * DVC + (ot - 16) * 64 + sl) * LL + s0 + cseg;
    *(uint4*)dst = *(uint4*)&buf[0];
    *(uint4*)(dst + 8) = *(uint4*)&buf[8];
  }
}

// ---------------- conv as implicit GEMM (bf16 MFMA, reg-prefetch) --------
__global__ __launch_bounds__(256) void conv_mfma(
    const unsigned short* __restrict__ xTp, const unsigned short* __restrict__ wtap,
    float* __restrict__ out) {
  __shared__ __align__(16) unsigned short as[64 * 64];
  __shared__ __align__(16) unsigned short bs[64 * 64];
  const int tid = threadIdx.x;
  const int lane = tid & 63, w = tid >> 6;
  const int n16 = lane & 15, quad = lane >> 4;
  const int ot = blockIdx.x;
  const int st = blockIdx.y;
  const int b = blockIdx.z;
  const int s0 = st * 64;
  const int h0 = st * 2;
  const int trow = tid >> 3;
  const int ck = tid & 7;

  const unsigned short* xb = xTp + (size_t)b * XPSTRIDE;
  const unsigned short* wbase = wtap + (size_t)(ot * 64) * 256;

  f32x4 acc[4];
#pragma unroll
  for (int nt = 0; nt < 4; ++nt) acc[nt] = (f32x4){0.f, 0.f, 0.f, 0.f};

  uint4 ra0, ra1, rb0, rb1;
  auto loadtile = [&](int it) {
    const int tap = it >> 2;
    const int c0 = (it & 3) * 64;
    const int dh = tap / 3 - 1;
    const int dw = tap - (tap / 3) * 3 - 1;
    const unsigned short* wt = wbase + (size_t)tap * 65536;
    ra0 = *(const uint4*)(wt + (size_t)trow * 256 + c0 + ck * 8);
    ra1 = *(const uint4*)(wt + (size_t)(trow + 32) * 256 + c0 + ck * 8);
    const int wp = (trow & 31) + dw + 1;
    rb0 = *(const uint4*)(xb + (size_t)((h0 + dh + 1) * 34 + wp) * 256 + c0 + ck * 8);
    rb1 = *(const uint4*)(xb + (size_t)((h0 + dh + 2) * 34 + wp) * 256 + c0 + ck * 8);
  };
  loadtile(0);
  for (int it = 0; it < 36; ++it) {
    __syncthreads();
    *(uint4*)&as[trow * 64 + ((ck ^ (trow & 7)) * 8)] = ra0;
    *(uint4*)&as[(trow + 32) * 64 + ((ck ^ (trow & 7)) * 8)] = ra1;
    *(uint4*)&bs[trow * 64 + ((ck ^ (trow & 7)) * 8)] = rb0;
    *(uint4*)&bs[(trow + 32) * 64 + ((ck ^ (trow & 7)) * 8)] = rb1;
    __syncthreads();
    if (it < 35) loadtile(it + 1);
    short8 a0 = *(const short8*)&as[(w * 16 + n16) * 64 + ((quad ^ (n16 & 7)) * 8)];
    short8 a1 = *(const short8*)&as[(w * 16 + n16) * 64 + (((quad + 4) ^ (n16 & 7)) * 8)];
#pragma unroll
    for (int nt = 0; nt < 4; ++nt) {
      short8 b0 = *(const short8*)&bs[(nt * 16 + n16) * 64 + ((quad ^ (n16 & 7)) * 8)];
      short8 b1 = *(const short8*)&bs[(nt * 16 + n16) * 64 + (((quad + 4) ^ (n16 & 7)) * 8)];
      acc[nt] = __builtin_amdgcn_mfma_f32_16x16x32_bf16(a0, b0, acc[nt], 0, 0, 0);
      acc[nt] = __builtin_amdgcn_mfma_f32_16x16x32_bf16(a1, b1, acc[nt], 0, 0, 0);
    }
  }
#pragma unroll
  for (int nt = 0; nt < 4; ++nt)
#pragma unroll
    for (int reg = 0; reg < 4; ++reg)
      out[((size_t)b * 512 + ot * 64 + w * 16 + quad * 4 + reg) * LL + s0 + nt * 16 + n16] =
          acc[nt][reg];
}

// ---------------- MFMA flash attention, fixed-max softmax ----------------
__global__ __launch_bounds__(256, 4) void attn_kernel(
    const unsigned short* __restrict__ qbf, const unsigned short* __restrict__ kbf,
    const unsigned short* __restrict__ vbf, const unsigned short* __restrict__ relTh,
    const unsigned short* __restrict__ relTw, unsigned short* __restrict__ abf) {
  __shared__ __align__(16) char smem[28672];
  unsigned short* ks = (unsigned short*)smem;             // [64][64] swizzled
  unsigned short* vs = (unsigned short*)(smem + 8192);    // [32][64] swizzled
  unsigned short* ps = (unsigned short*)(smem + 12288);   // 4x[16][64]; rht transient
  unsigned short* rwtT = (unsigned short*)(smem + 20480); // [64 m][64 row] swizzled
  float* obuf = (float*)smem;                             // [64][33] fp32 overlay

  const int tid = threadIdx.x;
  const int lane = tid & 63, w = tid >> 6;
  const int n16 = lane & 15, quad = lane >> 4;
  const int blk = blockIdx.x;
  const int bn = blk & 63, qb = blk >> 6;
  const int n = bn & 7, b = bn >> 3;
  const int s0 = qb * 64;
  const int aa = 2 * qb + (w >> 1);
  const int pb = (w & 1) * 16;

  const unsigned short* qbase = qbf + ((size_t)(b * 8 + n)) * LL * 64;
  const unsigned short* kbase = kbf + ((size_t)(b * 8 + n)) * LL * 64;
  const unsigned short* vbase = vbf + ((size_t)(b * 8 + n)) * 32 * LL;

  const int ck = tid & 7;
  const int trow = tid >> 3;

  // prefetch tile 0 (in flight during prologue)
  uint4 pk0 = *(const uint4*)(kbase + trow * 64 + ck * 8);
  uint4 pk1 = *(const uint4*)(kbase + (trow + 32) * 64 + ck * 8);
  uint4 pv = *(const uint4*)(vbase + (size_t)trow * LL + ck * 8);

  // ---- prologue: rel tables via MFMA; rw -> transposed LDS, rh transient --
  {
    const int sT = (pb + n16) * 32 + aa;
    short8 ra0 = *(const short8*)(qbase + (size_t)sT * 64 + quad * 8);
    short8 ra1 = *(const short8*)(qbase + (size_t)sT * 64 + 32 + quad * 8);
#pragma unroll
    for (int tbl = 0; tbl < 2; ++tbl) {
      const unsigned short* rel = tbl ? relTh : relTw;
      f32x4 acc[4];
#pragma unroll
      for (int mt = 0; mt < 4; ++mt) acc[mt] = (f32x4){0.f, 0.f, 0.f, 0.f};
#pragma unroll
      for (int mt = 0; mt < 4; ++mt) {
        short8 b0 = *(const short8*)(rel + (mt * 16 + n16) * 64 + quad * 8);
        short8 b1 = *(const short8*)(rel + (mt * 16 + n16) * 64 + 32 + quad * 8);
        acc[mt] = __builtin_amdgcn_mfma_f32_16x16x32_bf16(ra0, b0, acc[mt], 0, 0, 0);
        acc[mt] = __builtin_amdgcn_mfma_f32_16x16x32_bf16(ra1, b1, acc[mt], 0, 0, 0);
      }
      if (tbl == 0) {
#pragma unroll
        for (int mt = 0; mt < 4; ++mt)
#pragma unroll
          for (int reg = 0; reg < 4; ++reg)
            rwtT[(mt * 16 + n16) * 64 +
                 ((w * 16 + quad * 4 + reg) ^ ((n16 & 7) * 8))] = f2bf(acc[mt][reg]);
      } else {
#pragma unroll
        for (int mt = 0; mt < 4; ++mt)
#pragma unroll
          for (int reg = 0; reg < 4; ++reg)
            ps[(w * 16 + quad * 4 + reg) * 64 + mt * 16 + n16] = f2bf(acc[mt][reg]);
      }
    }
  }
  short8 qf0 = *(const short8*)(qbase + (size_t)(s0 + w * 16 + n16) * 64 + quad * 8);
  short8 qf1 = *(const short8*)(qbase + (size_t)(s0 + w * 16 + n16) * 64 + 32 + quad * 8);
  __syncthreads();
  // hoist rh bias: col index is kt-invariant -> 8 registers
  float rhreg[2][4];
#pragma unroll
  for (int tt1 = 0; tt1 < 2; ++tt1)
#pragma unroll
    for (int reg = 0; reg < 4; ++reg) {
      const int iL = quad * 4 + reg;
      rhreg[tt1][reg] = bf2f(ps[(w * 16 + iL) * 64 + tt1 * 16 + n16 + 31 - pb - iL]);
    }

  float lacc[4] = {0.f, 0.f, 0.f, 0.f};
  f32x4 oacc[2];
  oacc[0] = (f32x4){0.f, 0.f, 0.f, 0.f};
  oacc[1] = (f32x4){0.f, 0.f, 0.f, 0.f};

  unsigned short* psw = ps + w * 1024;
  const int rb = w * 16 + quad * 4;

  for (int kt64 = 0; kt64 < 16; ++kt64) {
    const int t0 = kt64 * 64;
    __syncthreads();
    *(uint4*)&ks[trow * 64 + ((ck ^ (trow & 7)) * 8)] = pk0;
    *(uint4*)&ks[(trow + 32) * 64 + ((ck ^ (trow & 7)) * 8)] = pk1;
    *(uint4*)&vs[trow * 64 + ((ck ^ (trow & 7)) * 8)] = pv;
    __syncthreads();
    if (kt64 < 15) {
      const unsigned short* kg = kbase + (size_t)(t0 + 64) * 64;
      pk0 = *(const uint4*)(kg + trow * 64 + ck * 8);
      pk1 = *(const uint4*)(kg + (trow + 32) * 64 + ck * 8);
      pv = *(const uint4*)(vbase + (size_t)trow * LL + t0 + 64 + ck * 8);
    }

    f32x4 sacc[4];
#pragma unroll
    for (int tt = 0; tt < 4; ++tt) sacc[tt] = (f32x4){0.f, 0.f, 0.f, 0.f};
#pragma unroll
    for (int tt = 0; tt < 4; ++tt) {
      short8 kb0 = *(const short8*)&ks[(tt * 16 + n16) * 64 + ((quad ^ (n16 & 7)) * 8)];
      short8 kb1 = *(const short8*)&ks[(tt * 16 + n16) * 64 + (((quad + 4) ^ (n16 & 7)) * 8)];
      sacc[tt] = __builtin_amdgcn_mfma_f32_16x16x32_bf16(qf0, kb0, sacc[tt], 0, 0, 0);
      sacc[tt] = __builtin_amdgcn_mfma_f32_16x16x32_bf16(qf1, kb1, sacc[tt], 0, 0, 0);
    }
    // rw bias: mw wave-uniform -> one b64 read per h, 4 consecutive rows
    float rwv[2][4];
#pragma unroll
    for (int h = 0; h < 2; ++h) {
      const int mw = (t0 >> 5) + h - aa + 31;
      const ushort4 rw4 = *(const ushort4*)&rwtT[mw * 64 + (rb ^ ((mw & 7) * 8))];
      rwv[h][0] = bf2f(rw4.x); rwv[h][1] = bf2f(rw4.y);
      rwv[h][2] = bf2f(rw4.z); rwv[h][3] = bf2f(rw4.w);
    }
    // P = exp2(s + rw + rh); store RTZ bf16 (d16_hi pattern)
#pragma unroll
    for (int tt = 0; tt < 4; ++tt)
#pragma unroll
      for (int reg = 0; reg < 4; ++reg) {
        const float e =
            __builtin_amdgcn_exp2f(sacc[tt][reg] + rwv[tt >> 1][reg] + rhreg[tt & 1][reg]);
        lacc[reg] += e;
        const int r = quad * 4 + reg;
        psw[r * 64 + (((tt * 2 + (n16 >> 3)) ^ (r & 7)) * 8) + (n16 & 7)] =
            (unsigned short)(__float_as_uint(e) >> 16);
      }
    __asm__ volatile("s_waitcnt lgkmcnt(0)" ::: "memory");
#pragma unroll
    for (int kt = 0; kt < 2; ++kt) {
      short8 pa = *(const short8*)&psw[n16 * 64 + (((quad + 4 * kt) ^ (n16 & 7)) * 8)];
#pragma unroll
      for (int ct = 0; ct < 2; ++ct) {
        short8 vb = *(const short8*)&vs[(ct * 16 + n16) * 64 + (((quad + 4 * kt) ^ (n16 & 7)) * 8)];
        oacc[ct] = __builtin_amdgcn_mfma_f32_16x16x32_bf16(pa, vb, oacc[ct], 0, 0, 0);
      }
    }
  }
  // deferred row-sum reduction
  float linv[4];
#pragma unroll
  for (int reg = 0; reg < 4; ++reg) {
    float l = lacc[reg];
#pragma unroll
    for (int m = 1; m < 16; m <<= 1) l += __shfl_xor(l, m, 16);
    linv[reg] = 1.0f / l;
  }
  __syncthreads();
#pragma unroll
  for (int ct = 0; ct < 2; ++ct)
#pragma unroll
    for (int reg = 0; reg < 4; ++reg)
      obuf[(w * 16 + quad * 4 + reg) * 33 + ct * 16 + n16] = oacc[ct][reg] * linv[reg];
  __syncthreads();
  {
    const int row = tid >> 2;
    const int cseg = (tid & 3) * 8;
    unsigned short buf8[8];
#pragma unroll
    for (int m = 0; m < 8; ++m) buf8[m] = f2bf(obuf[row * 33 + cseg + m]);
    *(uint4*)(abf + (((size_t)b * LL) + s0 + row) * 256 + n * 32 + cseg) = *(uint4*)&buf8[0];
  }
}

// ---------------- output projection as bf16 MFMA GEMM ----------------
__global__ __launch_bounds__(256) void proj_mfma(
    const unsigned short* __restrict__ abf, const unsigned short* __restrict__ woutbf,
    float* __restrict__ out) {
  __shared__ __align__(16) unsigned short as[64 * 64];
  __shared__ __align__(16) unsigned short bs[64 * 64];
  const int tid = threadIdx.x;
  const int lane = tid & 63, w = tid >> 6;
  const int n16 = lane & 15, quad = lane >> 4;
  const int ot = blockIdx.x;
  const int st = blockIdx.y;
  const int b = blockIdx.z;
  const int o0 = ot * 64;
  const int s0 = st * 64;
  const int trow = tid >> 3, ck = tid & 7;

  const unsigned short* ab = abf + ((size_t)b * LL + s0) * 256;
  const unsigned short* wt = woutbf + (size_t)o0 * 256;

  f32x4 acc[4];
#pragma unroll
  for (int nt = 0; nt < 4; ++nt) acc[nt] = (f32x4){0.f, 0.f, 0.f, 0.f};

  uint4 ra0, ra1, rb0, rb1;
  ra0 = *(const uint4*)(wt + (size_t)trow * 256 + ck * 8);
  ra1 = *(const uint4*)(wt + (size_t)(trow + 32) * 256 + ck * 8);
  rb0 = *(const uint4*)(ab + (size_t)trow * 256 + ck * 8);
  rb1 = *(const uint4*)(ab + (size_t)(trow + 32) * 256 + ck * 8);
#pragma unroll
  for (int kc = 0; kc < 4; ++kc) {
    __syncthreads();
    *(uint4*)&as[trow * 64 + ((ck ^ (trow & 7)) * 8)] = ra0;
    *(uint4*)&as[(trow + 32) * 64 + ((ck ^ (trow & 7)) * 8)] = ra1;
    *(uint4*)&bs[trow * 64 + ((ck ^ (trow & 7)) * 8)] = rb0;
    *(uint4*)&bs[(trow + 32) * 64 + ((ck ^ (trow & 7)) * 8)] = rb1;
    __syncthreads();
    if (kc < 3) {
      const int c0 = (kc + 1) * 64;
      ra0 = *(const uint4*)(wt + (size_t)trow * 256 + c0 + ck * 8);
      ra1 = *(const uint4*)(wt + (size_t)(trow + 32) * 256 + c0 + ck * 8);
      rb0 = *(const uint4*)(ab + (size_t)trow * 256 + c0 + ck * 8);
      rb1 = *(const uint4*)(ab + (size_t)(trow + 32) * 256 + c0 + ck * 8);
    }
    short8 a0 = *(const short8*)&as[(w * 16 + n16) * 64 + ((quad ^ (n16 & 7)) * 8)];
    short8 a1 = *(const short8*)&as[(w * 16 + n16) * 64 + (((quad + 4) ^ (n16 & 7)) * 8)];
#pragma unroll
    for (int nt = 0; nt < 4; ++nt) {
      short8 b0 = *(const short8*)&bs[(nt * 16 + n16) * 64 + ((quad ^ (n16 & 7)) * 8)];
      short8 b1 = *(const short8*)&bs[(nt * 16 + n16) * 64 + (((quad + 4) ^ (n16 & 7)) * 8)];
      acc[nt] = __builtin_amdgcn_mfma_f32_16x16x32_bf16(a0, b0, acc[nt], 0, 0, 0);
      acc[nt] = __builtin_amdgcn_mfma_f32_16x16x32_bf16(a1, b1, acc[nt], 0, 0, 0);
    }
  }
#pragma unroll
  for (int nt = 0; nt < 4; ++nt)
#pragma unroll
    for (int reg = 0; reg < 4; ++reg)
      out[((size_t)b * 512 + 256 + o0 + w * 16 + quad * 4 + reg) * LL + s0 + nt * 16 + n16] =
          acc[nt][reg];
}

extern "C" void kernel_launch(void* const* d_in, const int* in_sizes, int n_in,
                              void* d_out, int out_size, void* d_ws, size_t ws_size,
                              hipStream_t stream) {
  const float* x     = (const float*)d_in[0];
  const float* wqkv  = (const float*)d_in[1];
  const float* wconv = (const float*)d_in[2];
  const float* wout  = (const float*)d_in[3];
  const float* krh   = (const float*)d_in[4];
  const float* krw   = (const float*)d_in[5];
  float* out = (float*)d_out;

  unsigned short* qbf = (unsigned short*)d_ws;
  unsigned short* kbf = qbf + (size_t)NB * 8 * LL * 64;
  unsigned short* vbf = kbf + (size_t)NB * 8 * LL * 64;
  unsigned short* abf = vbf + (size_t)NB * DVC * LL;
  unsigned short* relTh = abf + (size_t)NB * LL * DVC;
  unsigned short* relTw = relTh + 4096;
  unsigned short* xTp = relTw + 4096;
  unsigned short* wtap = xTp + (size_t)NB * XPSTRIDE;
  unsigned short* wqbf = wtap + 589824;
  unsigned short* woutbf = wqbf + 327680;

  prep_weights<<<dim3(3872), 256, 0, stream>>>(wconv, wqkv, wout, krh, krw,
                                               wtap, wqbf, woutbf, relTh, relTw);
  xpad_border<<<dim3(1056), 256, 0, stream>>>(xTp);
  xpad_interior<<<dim3(16, 8), 256, 0, stream>>>(x, xTp);
  qkv_mfma<<<dim3(20, 16, NB), 256, 0, stream>>>(xTp, wqbf, qbf, kbf, vbf);
  conv_mfma<<<dim3(4, 16, NB), 256, 0, stream>>>(xTp, wtap, out);
  attn_kernel<<<dim3(1024), 256, 0, stream>>>(qbf, kbf, vbf, relTh, relTw, abf);
  proj_mfma<<<dim3(4, 16, NB), 256, 0, stream>>>(abf, woutbf, out);
}